// Round 1
// baseline (11351.696 us; speedup 1.0000x reference)
//
#include <hip/hip_runtime.h>
#include <math.h>

#define N_PTS 120000
#define M_PTS 30000
#define TS (1 << 18)
#define TSM (TS - 1)
#define RROWS 16

// ---------------- workspace layout (bytes) ----------------
#define OFF_KEY   0ull
#define OFF_CNT   (OFF_KEY + (unsigned long long)TS * 8)          // 2 MB
#define OFF_SUM   (OFF_CNT + (unsigned long long)TS * 4)          // 3 MB
#define OFF_SEL   (OFF_SUM + (unsigned long long)TS * 4)          // 4 MB
#define OFF_AUX   (OFF_SEL + (unsigned long long)N_PTS * 4)
#define OFF_DOWNC (OFF_AUX + 256ull)
#define OFF_DOWNN (OFF_DOWNC + (unsigned long long)M_PTS * 3 * 4)
#define OFF_GENC  (OFF_DOWNN + (unsigned long long)M_PTS * 3 * 4)
#define OFF_STYLE (OFF_GENC + 1024ull)
#define OFF_TESF  (OFF_STYLE + 1024ull)
#define OFF_X     (OFF_TESF + 1024ull)
// OFF_X + 30000*256*4 = ~36.1 MB total

struct Aux {
  unsigned mn_enc[3];
  unsigned mx_enc[3];
  float mn[3];
  float pad;
  double vs;
};

// order-preserving float<->uint encoding for atomic min/max
__device__ __forceinline__ unsigned encf(float v) {
  unsigned u = __float_as_uint(v);
  return (u & 0x80000000u) ? ~u : (u | 0x80000000u);
}
__device__ __forceinline__ float decf(unsigned u) {
  unsigned v = (u & 0x80000000u) ? (u & 0x7fffffffu) : ~u;
  return __uint_as_float(v);
}

// ---------------- downsample kernels ----------------

__global__ void k_init(unsigned long long* __restrict__ key, int* __restrict__ cnt,
                       int* __restrict__ sum, int* __restrict__ sel, Aux* aux) {
  int i = blockIdx.x * blockDim.x + threadIdx.x;
  if (i < TS) { key[i] = 0ull; cnt[i] = 0; sum[i] = 0; }
  if (i < N_PTS) sel[i] = 0;
  if (i < 3) { aux->mn_enc[i] = 0xFFFFFFFFu; aux->mx_enc[i] = 0u; }
}

__global__ void k_minmax(const float* __restrict__ pts, Aux* aux) {
  __shared__ unsigned smn[3], smx[3];
  int t = threadIdx.x;
  if (t < 3) { smn[t] = 0xFFFFFFFFu; smx[t] = 0u; }
  __syncthreads();
  unsigned lmn[3] = {0xFFFFFFFFu, 0xFFFFFFFFu, 0xFFFFFFFFu};
  unsigned lmx[3] = {0u, 0u, 0u};
  for (int i = blockIdx.x * blockDim.x + t; i < N_PTS; i += gridDim.x * blockDim.x) {
    #pragma unroll
    for (int c = 0; c < 3; c++) {
      unsigned e = encf(pts[i * 3 + c]);
      lmn[c] = min(lmn[c], e);
      lmx[c] = max(lmx[c], e);
    }
  }
  #pragma unroll
  for (int c = 0; c < 3; c++) { atomicMin(&smn[c], lmn[c]); atomicMax(&smx[c], lmx[c]); }
  __syncthreads();
  if (t < 3) { atomicMin(&aux->mn_enc[t], smn[t]); atomicMax(&aux->mx_enc[t], smx[t]); }
}

__global__ void k_vs(Aux* aux) {
  double prod = 1.0;
  for (int c = 0; c < 3; c++) {
    float mnf = decf(aux->mn_enc[c]);
    float mxf = decf(aux->mx_enc[c]);
    aux->mn[c] = mnf;
    double r = (double)mxf - (double)mnf;
    if (r < 1e-6) r = 1.0;
    prod *= r;
  }
  double vs = pow(prod / (double)M_PTS, 1.0 / 3.0) * 1.2;
  if (vs < 1e-6) vs = 0.001;
  aux->vs = vs;
}

__global__ void k_build(const float* __restrict__ pts, const Aux* aux,
                        unsigned long long* __restrict__ key, int* __restrict__ cnt,
                        int* __restrict__ sum) {
  int i = blockIdx.x * blockDim.x + threadIdx.x;
  if (i >= N_PTS) return;
  double vs = aux->vs;
  unsigned h = 0u;
  const unsigned mulc[3] = {73856093u, 19349663u, 83492791u};
  #pragma unroll
  for (int c = 0; c < 3; c++) {
    int vi = (int)floor(((double)pts[i * 3 + c] - (double)aux->mn[c]) / vs);
    h ^= (unsigned)vi * mulc[c];
  }
  unsigned long long want = 0x100000000ull | (unsigned long long)h;
  unsigned slot = (h * 2654435761u) >> 14;  // top 18 bits
  for (;;) {
    unsigned long long cur = key[slot];
    if (cur == want) break;
    if (cur == 0ull) {
      unsigned long long prev = atomicCAS(&key[slot], 0ull, want);
      if (prev == 0ull || prev == want) break;
    }
    slot = (slot + 1) & TSM;
  }
  atomicAdd(&cnt[slot], 1);
  atomicAdd(&sum[slot], i);
}

__global__ void k_reps(const unsigned long long* __restrict__ key, const int* __restrict__ cnt,
                       const int* __restrict__ sum, int* __restrict__ sel) {
  int s = blockIdx.x * blockDim.x + threadIdx.x;
  if (s >= TS) return;
  if (key[s] != 0ull) {
    int rep = sum[s] / cnt[s];  // nonneg -> floor division, matches //
    sel[rep] = 1;
  }
}

// single block, 256 threads: stable selection order + gather
__global__ void k_select(const int* __restrict__ sel, const float* __restrict__ pts,
                         float* __restrict__ down, float* __restrict__ idxout) {
  __shared__ int cs[256];
  __shared__ int Ktot;
  int t = threadIdx.x;
  const int CH = (N_PTS + 255) / 256;  // 469
  int s0 = t * CH;
  int s1 = min(s0 + CH, N_PTS);
  int c = 0;
  for (int i = s0; i < s1; i++) c += sel[i];
  cs[t] = c;
  __syncthreads();
  if (t == 0) {
    int acc = 0;
    for (int k = 0; k < 256; k++) { int v = cs[k]; cs[k] = acc; acc += v; }
    Ktot = acc;
  }
  __syncthreads();
  int K = Ktot;
  int sr = cs[t];       // selected before my chunk
  int ur = s0 - sr;     // unselected before my chunk
  for (int i = s0; i < s1; i++) {
    int slot = sel[i] ? (sr++) : (K + ur++);
    if (slot < M_PTS) {
      down[slot * 3 + 0] = pts[i * 3 + 0];
      down[slot * 3 + 1] = pts[i * 3 + 1];
      down[slot * 3 + 2] = pts[i * 3 + 2];
      if (idxout) idxout[slot] = (float)i;
    }
  }
}

// ---------------- network kernels ----------------

__global__ void k_zero_g(unsigned* __restrict__ g) { g[threadIdx.x] = 0u; }

// style per-point MLP (3->64->128->256) + max pool; grid-stride over points
__global__ void k_style_pp(const float* __restrict__ down,
                           const float* __restrict__ w1, const float* __restrict__ b1,
                           const float* __restrict__ w2, const float* __restrict__ b2,
                           const float* __restrict__ w3, const float* __restrict__ b3,
                           unsigned* __restrict__ genc) {
  __shared__ float l1[64], l2[128], pc[3];
  int t = threadIdx.x;
  float lmax = -3.4e38f;
  for (int p = blockIdx.x; p < M_PTS; p += gridDim.x) {
    __syncthreads();
    if (t < 3) pc[t] = down[p * 3 + t];
    __syncthreads();
    if (t < 64)
      l1[t] = fmaxf(b1[t] + pc[0] * w1[t] + pc[1] * w1[64 + t] + pc[2] * w1[128 + t], 0.f);
    __syncthreads();
    if (t < 128) {
      float s = b2[t];
      for (int k = 0; k < 64; k++) s += l1[k] * w2[k * 128 + t];
      l2[t] = fmaxf(s, 0.f);
    }
    __syncthreads();
    float s = b3[t];
    for (int k = 0; k < 128; k++) s += l2[k] * w3[k * 256 + t];
    lmax = fmaxf(lmax, s);
  }
  atomicMax(&genc[t], encf(lmax));
}

// style MLP: 256 -> 512 relu -> 256 relu ; one block, 512 threads
__global__ void k_style_mlp(const unsigned* __restrict__ genc,
                            const float* __restrict__ w1, const float* __restrict__ b1,
                            const float* __restrict__ w2, const float* __restrict__ b2,
                            float* __restrict__ style) {
  __shared__ float g[256], s1[512];
  int t = threadIdx.x;
  if (t < 256) g[t] = decf(genc[t]);
  __syncthreads();
  float h = b1[t];
  for (int k = 0; k < 256; k++) h += g[k] * w1[k * 512 + t];
  s1[t] = fmaxf(h, 0.f);
  __syncthreads();
  if (t < 256) {
    float o = b2[t];
    for (int k = 0; k < 512; k++) o += s1[k] * w2[k * 256 + t];
    style[t] = fmaxf(o, 0.f);
  }
}

// time embedding @ tp_w + tp_b + style @ sp_w + sp_b  ; one block, 256 threads
__global__ void k_tesf(const int* __restrict__ tstep, int b, const float* __restrict__ style,
                       const float* __restrict__ tpw, const float* __restrict__ tpb,
                       const float* __restrict__ spw, const float* __restrict__ spb,
                       float* __restrict__ tesf) {
  __shared__ float te[128], st[256];
  int t = threadIdx.x;
  float tf = (float)tstep[b];
  if (t < 64) {
    const float cfr = (float)(-9.210340371976184 / 63.0);  // -ln(10000)/(half-1)
    float fr = expf((float)t * cfr);
    float ang = tf * fr;
    te[t] = sinf(ang);
    te[64 + t] = cosf(ang);
  }
  st[t] = style[t];
  __syncthreads();
  float v = tpb[t];
  for (int k = 0; k < 128; k++) v += te[k] * tpw[k * 256 + t];
  float v2 = spb[t];
  for (int k = 0; k < 256; k++) v2 += st[k] * spw[k * 256 + t];
  tesf[t] = v + v2;
}

// point encoder 3->128->256(relu)->256(linear) + tesf ; one block per point
__global__ void k_pe(const float* __restrict__ down,
                     const float* __restrict__ w1, const float* __restrict__ b1,
                     const float* __restrict__ w2, const float* __restrict__ b2,
                     const float* __restrict__ w3, const float* __restrict__ b3,
                     const float* __restrict__ tesf, float* __restrict__ x) {
  __shared__ float l1[128], l2[256], pc[3];
  int p = blockIdx.x, t = threadIdx.x;
  if (t < 3) pc[t] = down[p * 3 + t];
  __syncthreads();
  if (t < 128)
    l1[t] = fmaxf(b1[t] + pc[0] * w1[t] + pc[1] * w1[128 + t] + pc[2] * w1[256 + t], 0.f);
  __syncthreads();
  float s = b2[t];
  for (int k = 0; k < 128; k++) s += l1[k] * w2[k * 256 + t];
  l2[t] = fmaxf(s, 0.f);
  __syncthreads();
  float o = b3[t];
  for (int k = 0; k < 256; k++) o += l2[k] * w3[k * 256 + t];
  x[(size_t)p * 256 + t] = o + tesf[t];
}

// residual block: x += relu(x@W1+b1)@W2+b2 ; 16 rows per block, in place
__global__ void k_res(float* __restrict__ x,
                      const float* __restrict__ w1, const float* __restrict__ b1,
                      const float* __restrict__ w2, const float* __restrict__ b2) {
  __shared__ float xs[RROWS][256];   // 16 KB
  __shared__ float hs[RROWS][512];   // 32 KB
  int t = threadIdx.x;
  int base = blockIdx.x * RROWS;
  #pragma unroll
  for (int r = 0; r < RROWS; r++) xs[r][t] = x[(size_t)(base + r) * 256 + t];
  __syncthreads();

  float a0[RROWS], a1[RROWS];
  float bj0 = b1[t], bj1 = b1[t + 256];
  #pragma unroll
  for (int r = 0; r < RROWS; r++) { a0[r] = bj0; a1[r] = bj1; }
  for (int k = 0; k < 256; k++) {
    float w0 = w1[k * 512 + t];
    float wq = w1[k * 512 + t + 256];
    #pragma unroll
    for (int r = 0; r < RROWS; r++) {
      float xv = xs[r][k];
      a0[r] += xv * w0;
      a1[r] += xv * wq;
    }
  }
  #pragma unroll
  for (int r = 0; r < RROWS; r++) {
    hs[r][t] = fmaxf(a0[r], 0.f);
    hs[r][t + 256] = fmaxf(a1[r], 0.f);
  }
  __syncthreads();

  float a2[RROWS];
  float bj = b2[t];
  #pragma unroll
  for (int r = 0; r < RROWS; r++) a2[r] = bj;
  for (int k = 0; k < 512; k++) {
    float w = w2[k * 256 + t];
    #pragma unroll
    for (int r = 0; r < RROWS; r++) a2[r] += hs[r][k] * w;
  }
  #pragma unroll
  for (int r = 0; r < RROWS; r++) x[(size_t)(base + r) * 256 + t] = a2[r] + xs[r][t];
}

// output head 256->256 relu ->128 relu ->3 ; one block per point
__global__ void k_out(const float* __restrict__ x,
                      const float* __restrict__ w1, const float* __restrict__ b1,
                      const float* __restrict__ w2, const float* __restrict__ b2,
                      const float* __restrict__ w3, const float* __restrict__ b3,
                      float* __restrict__ pred) {
  __shared__ float xr[256], l1[256], l2[128];
  int p = blockIdx.x, t = threadIdx.x;
  xr[t] = x[(size_t)p * 256 + t];
  __syncthreads();
  float s = b1[t];
  for (int k = 0; k < 256; k++) s += xr[k] * w1[k * 256 + t];
  l1[t] = fmaxf(s, 0.f);
  __syncthreads();
  if (t < 128) {
    float s2 = b2[t];
    for (int k = 0; k < 256; k++) s2 += l1[k] * w2[k * 128 + t];
    l2[t] = fmaxf(s2, 0.f);
  }
  __syncthreads();
  if (t < 3) {
    float o = b3[t];
    for (int k = 0; k < 128; k++) o += l2[k] * w3[k * 3 + t];
    pred[(size_t)p * 3 + t] = o;
  }
}

// ---------------- launch ----------------

extern "C" void kernel_launch(void* const* d_in, const int* in_sizes, int n_in,
                              void* d_out, int out_size, void* d_ws, size_t ws_size,
                              hipStream_t stream) {
  const float* noisy = (const float*)d_in[0];
  const int* tstep = (const int*)d_in[1];
  const float* cond = (const float*)d_in[2];
  const float* se_w1 = (const float*)d_in[3];  const float* se_b1 = (const float*)d_in[4];
  const float* se_w2 = (const float*)d_in[5];  const float* se_b2 = (const float*)d_in[6];
  const float* se_w3 = (const float*)d_in[7];  const float* se_b3 = (const float*)d_in[8];
  const float* sm_w1 = (const float*)d_in[9];  const float* sm_b1 = (const float*)d_in[10];
  const float* sm_w2 = (const float*)d_in[11]; const float* sm_b2 = (const float*)d_in[12];
  const float* pe_w1 = (const float*)d_in[13]; const float* pe_b1 = (const float*)d_in[14];
  const float* pe_w2 = (const float*)d_in[15]; const float* pe_b2 = (const float*)d_in[16];
  const float* pe_w3 = (const float*)d_in[17]; const float* pe_b3 = (const float*)d_in[18];
  const float* tp_w = (const float*)d_in[19];  const float* tp_b = (const float*)d_in[20];
  const float* sp_w = (const float*)d_in[21];  const float* sp_b = (const float*)d_in[22];
  const float* lw1 = (const float*)d_in[23];   const float* lb1 = (const float*)d_in[24];
  const float* lw2 = (const float*)d_in[25];   const float* lb2 = (const float*)d_in[26];
  const float* ow1 = (const float*)d_in[27];   const float* ob1 = (const float*)d_in[28];
  const float* ow2 = (const float*)d_in[29];   const float* ob2 = (const float*)d_in[30];
  const float* ow3 = (const float*)d_in[31];   const float* ob3 = (const float*)d_in[32];

  char* ws = (char*)d_ws;
  unsigned long long* key = (unsigned long long*)(ws + OFF_KEY);
  int* cnt = (int*)(ws + OFF_CNT);
  int* sum = (int*)(ws + OFF_SUM);
  int* sel = (int*)(ws + OFF_SEL);
  Aux* aux = (Aux*)(ws + OFF_AUX);
  float* downC = (float*)(ws + OFF_DOWNC);
  float* downN = (float*)(ws + OFF_DOWNN);
  unsigned* genc = (unsigned*)(ws + OFF_GENC);
  float* style = (float*)(ws + OFF_STYLE);
  float* tesf = (float*)(ws + OFF_TESF);
  float* x = (float*)(ws + OFF_X);

  float* pred = (float*)d_out;
  float* idxout = (float*)d_out + (size_t)2 * M_PTS * 3;

  for (int b = 0; b < 2; b++) {
    // --- condition cloud downsample ---
    const float* cp = cond + (size_t)b * N_PTS * 3;
    k_init<<<TS / 256, 256, 0, stream>>>(key, cnt, sum, sel, aux);
    k_minmax<<<256, 256, 0, stream>>>(cp, aux);
    k_vs<<<1, 1, 0, stream>>>(aux);
    k_build<<<(N_PTS + 255) / 256, 256, 0, stream>>>(cp, aux, key, cnt, sum);
    k_reps<<<TS / 256, 256, 0, stream>>>(key, cnt, sum, sel);
    k_select<<<1, 256, 0, stream>>>(sel, cp, downC, (float*)nullptr);

    // --- noisy cloud downsample (also writes idx output as floats) ---
    const float* npts = noisy + (size_t)b * N_PTS * 3;
    k_init<<<TS / 256, 256, 0, stream>>>(key, cnt, sum, sel, aux);
    k_minmax<<<256, 256, 0, stream>>>(npts, aux);
    k_vs<<<1, 1, 0, stream>>>(aux);
    k_build<<<(N_PTS + 255) / 256, 256, 0, stream>>>(npts, aux, key, cnt, sum);
    k_reps<<<TS / 256, 256, 0, stream>>>(key, cnt, sum, sel);
    k_select<<<1, 256, 0, stream>>>(sel, npts, downN, idxout + (size_t)b * M_PTS);

    // --- network ---
    k_zero_g<<<1, 256, 0, stream>>>(genc);
    k_style_pp<<<256, 256, 0, stream>>>(downC, se_w1, se_b1, se_w2, se_b2, se_w3, se_b3, genc);
    k_style_mlp<<<1, 512, 0, stream>>>(genc, sm_w1, sm_b1, sm_w2, sm_b2, style);
    k_tesf<<<1, 256, 0, stream>>>(tstep, b, style, tp_w, tp_b, sp_w, sp_b, tesf);
    k_pe<<<M_PTS, 256, 0, stream>>>(downN, pe_w1, pe_b1, pe_w2, pe_b2, pe_w3, pe_b3, tesf, x);
    for (int l = 0; l < 6; l++)
      k_res<<<M_PTS / RROWS, 256, 0, stream>>>(x, lw1 + (size_t)l * 256 * 512, lb1 + (size_t)l * 512,
                                               lw2 + (size_t)l * 512 * 256, lb2 + (size_t)l * 256);
    k_out<<<M_PTS, 256, 0, stream>>>(x, ow1, ob1, ow2, ob2, ow3, ob3, pred + (size_t)b * M_PTS * 3);
  }
}

// Round 2
// 3313.679 us; speedup vs baseline: 3.4257x; 3.4257x over previous
//
#include <hip/hip_runtime.h>
#include <math.h>

#define N_PTS 120000
#define M_PTS 30000
#define M_PAD 30016              // 469 chunks * 64 rows, 1876 * 16
#define TS (1 << 18)
#define TSM (TS - 1)
#define RROWS 16

typedef __attribute__((ext_vector_type(8))) short bf16x8_t;
typedef __attribute__((ext_vector_type(4))) float f32x4_t;

// ---------------- workspace layout (bytes) ----------------
#define OFF_KEY   0ull
#define OFF_CNT   (OFF_KEY + (unsigned long long)TS * 8)            // 2 MB
#define OFF_SUM   (OFF_CNT + (unsigned long long)TS * 4)            // 3 MB
#define OFF_SEL   (OFF_SUM + (unsigned long long)TS * 4)            // 4 MB
#define OFF_AUX   (OFF_SEL + (unsigned long long)N_PTS * 4)
#define OFF_DOWNC (OFF_AUX + 256ull)                                 // 2 batches
#define OFF_DOWNN (OFF_DOWNC + 2ull * M_PTS * 3 * 4)                 // 2 batches
#define OFF_GENC  (OFF_DOWNN + 2ull * M_PTS * 3 * 4)
#define OFF_STYLE (OFF_GENC + 1024ull)
#define OFF_TESF  (OFF_STYLE + 1024ull)
#define OFF_X     6117888ull                                         // 256B aligned
#define OFF_W1P   (OFF_X + (unsigned long long)M_PAD * 256 * 4)      // 36854272
#define OFF_W2P   (OFF_W1P + 1572864ull)
#define WS_NEED   (OFF_W2P + 1572864ull)                             // 40000000

struct Aux {
  unsigned mn_enc[3];
  unsigned mx_enc[3];
  float mn[3];
  float pad;
  double vs;
};

__device__ __forceinline__ unsigned encf(float v) {
  unsigned u = __float_as_uint(v);
  return (u & 0x80000000u) ? ~u : (u | 0x80000000u);
}
__device__ __forceinline__ float decf(unsigned u) {
  unsigned v = (u & 0x80000000u) ? (u & 0x7fffffffu) : ~u;
  return __uint_as_float(v);
}
__device__ __forceinline__ unsigned short f2bf(float f) {
  unsigned u = __float_as_uint(f);
  u += 0x7fffu + ((u >> 16) & 1u);
  return (unsigned short)(u >> 16);
}

// ---------------- downsample kernels ----------------

__global__ void k_init(unsigned long long* __restrict__ key, int* __restrict__ cnt,
                       int* __restrict__ sum, int* __restrict__ sel, Aux* aux) {
  int i = blockIdx.x * blockDim.x + threadIdx.x;
  if (i < TS) { key[i] = 0ull; cnt[i] = 0; sum[i] = 0; }
  if (i < N_PTS) sel[i] = 0;
  if (i < 3) { aux->mn_enc[i] = 0xFFFFFFFFu; aux->mx_enc[i] = 0u; }
}

__global__ void k_minmax(const float* __restrict__ pts, Aux* aux) {
  __shared__ unsigned smn[3], smx[3];
  int t = threadIdx.x;
  if (t < 3) { smn[t] = 0xFFFFFFFFu; smx[t] = 0u; }
  __syncthreads();
  unsigned lmn[3] = {0xFFFFFFFFu, 0xFFFFFFFFu, 0xFFFFFFFFu};
  unsigned lmx[3] = {0u, 0u, 0u};
  for (int i = blockIdx.x * blockDim.x + t; i < N_PTS; i += gridDim.x * blockDim.x) {
    #pragma unroll
    for (int c = 0; c < 3; c++) {
      unsigned e = encf(pts[i * 3 + c]);
      lmn[c] = min(lmn[c], e);
      lmx[c] = max(lmx[c], e);
    }
  }
  #pragma unroll
  for (int c = 0; c < 3; c++) { atomicMin(&smn[c], lmn[c]); atomicMax(&smx[c], lmx[c]); }
  __syncthreads();
  if (t < 3) { atomicMin(&aux->mn_enc[t], smn[t]); atomicMax(&aux->mx_enc[t], smx[t]); }
}

__global__ void k_vs(Aux* aux) {
  double prod = 1.0;
  for (int c = 0; c < 3; c++) {
    float mnf = decf(aux->mn_enc[c]);
    float mxf = decf(aux->mx_enc[c]);
    aux->mn[c] = mnf;
    double r = (double)mxf - (double)mnf;
    if (r < 1e-6) r = 1.0;
    prod *= r;
  }
  double vs = pow(prod / (double)M_PTS, 1.0 / 3.0) * 1.2;
  if (vs < 1e-6) vs = 0.001;
  aux->vs = vs;
}

__global__ void k_build(const float* __restrict__ pts, const Aux* aux,
                        unsigned long long* __restrict__ key, int* __restrict__ cnt,
                        int* __restrict__ sum) {
  int i = blockIdx.x * blockDim.x + threadIdx.x;
  if (i >= N_PTS) return;
  double vs = aux->vs;
  unsigned h = 0u;
  const unsigned mulc[3] = {73856093u, 19349663u, 83492791u};
  #pragma unroll
  for (int c = 0; c < 3; c++) {
    int vi = (int)floor(((double)pts[i * 3 + c] - (double)aux->mn[c]) / vs);
    h ^= (unsigned)vi * mulc[c];
  }
  unsigned long long want = 0x100000000ull | (unsigned long long)h;
  unsigned slot = (h * 2654435761u) >> 14;
  for (;;) {
    unsigned long long cur = key[slot];
    if (cur == want) break;
    if (cur == 0ull) {
      unsigned long long prev = atomicCAS(&key[slot], 0ull, want);
      if (prev == 0ull || prev == want) break;
    }
    slot = (slot + 1) & TSM;
  }
  atomicAdd(&cnt[slot], 1);
  atomicAdd(&sum[slot], i);
}

__global__ void k_reps(const unsigned long long* __restrict__ key, const int* __restrict__ cnt,
                       const int* __restrict__ sum, int* __restrict__ sel) {
  int s = blockIdx.x * blockDim.x + threadIdx.x;
  if (s >= TS) return;
  if (key[s] != 0ull) {
    int rep = sum[s] / cnt[s];
    sel[rep] = 1;
  }
}

// 1024 threads, shfl-scan based stable select
__global__ void k_select(const int* __restrict__ sel, const float* __restrict__ pts,
                         float* __restrict__ down, float* __restrict__ idxout) {
  __shared__ int wtot[16], wbase[16];
  __shared__ int Ktot;
  int t = threadIdx.x;
  const int CH = 118;  // 1024*118 >= 120000
  int s0 = t * CH;
  int s1 = min(s0 + CH, N_PTS);
  int c = 0;
  for (int i = s0; i < s1; i++) c += sel[i];
  int lane = t & 63, wid = t >> 6;
  int incl = c;
  for (int d = 1; d < 64; d <<= 1) {
    int v = __shfl_up(incl, d, 64);
    if (lane >= d) incl += v;
  }
  if (lane == 63) wtot[wid] = incl;
  __syncthreads();
  if (t == 0) {
    int a = 0;
    for (int k = 0; k < 16; k++) { wbase[k] = a; a += wtot[k]; }
    Ktot = a;
  }
  __syncthreads();
  int excl = wbase[wid] + incl - c;
  int K = Ktot;
  int sr = excl, ur = s0 - excl;
  for (int i = s0; i < s1; i++) {
    int slot = sel[i] ? (sr++) : (K + ur++);
    if (slot < M_PTS) {
      down[slot * 3 + 0] = pts[i * 3 + 0];
      down[slot * 3 + 1] = pts[i * 3 + 1];
      down[slot * 3 + 2] = pts[i * 3 + 2];
      if (idxout) idxout[slot] = (float)i;
    }
  }
}

// ---------------- weight packing (MFMA fragment order, bf16) ----------------
// w1p[l][ks<8][nt<32][lane<64][j<8] = lw1[l][ks*32+(lane>>4)*8+j][nt*16+(lane&15)]
__global__ void k_pack1(const float* __restrict__ lw1, unsigned short* __restrict__ w1p) {
  int idx = blockIdx.x * 256 + threadIdx.x;  // 98304
  int lane = idx & 63, nt = (idx >> 6) & 31, ks = (idx >> 11) & 7, l = idx >> 14;
  const float* src = lw1 + (size_t)l * 131072;
  int cc = nt * 16 + (lane & 15);
  int k0 = ks * 32 + ((lane >> 4) << 3);
  unsigned short* dst = w1p + (size_t)idx * 8;
  #pragma unroll
  for (int j = 0; j < 8; j++) dst[j] = f2bf(src[(size_t)(k0 + j) * 512 + cc]);
}
// w2p[l][ks<16][nt<16][lane][j] = lw2[l][ks*32+(lane>>4)*8+j][nt*16+(lane&15)]
__global__ void k_pack2(const float* __restrict__ lw2, unsigned short* __restrict__ w2p) {
  int idx = blockIdx.x * 256 + threadIdx.x;  // 98304
  int lane = idx & 63, nt = (idx >> 6) & 15, ks = (idx >> 10) & 15, l = idx >> 14;
  const float* src = lw2 + (size_t)l * 131072;
  int cc = nt * 16 + (lane & 15);
  int k0 = ks * 32 + ((lane >> 4) << 3);
  unsigned short* dst = w2p + (size_t)idx * 8;
  #pragma unroll
  for (int j = 0; j < 8; j++) dst[j] = f2bf(src[(size_t)(k0 + j) * 256 + cc]);
}

// ---------------- network kernels ----------------

__global__ void k_zero_g(unsigned* __restrict__ g) { g[threadIdx.x] = 0u; }

// style per-point MLP, 16 pts/block, transposed LDS tiles
__global__ void k_style_ppt(const float* __restrict__ down,
                            const float* __restrict__ w1, const float* __restrict__ b1,
                            const float* __restrict__ w2, const float* __restrict__ b2,
                            const float* __restrict__ w3, const float* __restrict__ b3,
                            unsigned* __restrict__ genc) {
  __shared__ float pc[16][3];
  __shared__ float l1t[64][20];
  __shared__ float l2t[128][20];
  int t = threadIdx.x;
  int p0 = blockIdx.x * 16;
  if (t < 48) pc[t / 3][t % 3] = down[p0 * 3 + t];
  __syncthreads();
  {
    int c = t & 63, rg = (t >> 6) * 4;
    float w0 = w1[c], wx = w1[64 + c], wy = w1[128 + c], bb = b1[c];
    #pragma unroll
    for (int j = 0; j < 4; j++) {
      int r = rg + j;
      l1t[c][r] = fmaxf(bb + pc[r][0] * w0 + pc[r][1] * wx + pc[r][2] * wy, 0.f);
    }
  }
  __syncthreads();
  {
    int c = t & 127, rg = (t >> 7) * 8;
    float acc[8], bb = b2[c];
    #pragma unroll
    for (int j = 0; j < 8; j++) acc[j] = bb;
    for (int k = 0; k < 64; k++) {
      float wv = w2[k * 128 + c];
      f32x4_t v0 = *(const f32x4_t*)&l1t[k][rg];
      f32x4_t v1 = *(const f32x4_t*)&l1t[k][rg + 4];
      acc[0] += v0[0] * wv; acc[1] += v0[1] * wv; acc[2] += v0[2] * wv; acc[3] += v0[3] * wv;
      acc[4] += v1[0] * wv; acc[5] += v1[1] * wv; acc[6] += v1[2] * wv; acc[7] += v1[3] * wv;
    }
    #pragma unroll
    for (int j = 0; j < 8; j++) l2t[c][rg + j] = fmaxf(acc[j], 0.f);
  }
  __syncthreads();
  {
    int c = t;
    float acc[16], bb = b3[c];
    #pragma unroll
    for (int j = 0; j < 16; j++) acc[j] = bb;
    for (int k = 0; k < 128; k++) {
      float wv = w3[k * 256 + c];
      #pragma unroll
      for (int h = 0; h < 4; h++) {
        f32x4_t v = *(const f32x4_t*)&l2t[k][h * 4];
        acc[h * 4 + 0] += v[0] * wv; acc[h * 4 + 1] += v[1] * wv;
        acc[h * 4 + 2] += v[2] * wv; acc[h * 4 + 3] += v[3] * wv;
      }
    }
    float m = acc[0];
    #pragma unroll
    for (int j = 1; j < 16; j++) m = fmaxf(m, acc[j]);
    atomicMax(&genc[c], encf(m));
  }
}

// style MLP: 256 -> 512 relu -> 256 relu ; one block, 512 threads
__global__ void k_style_mlp(const unsigned* __restrict__ genc,
                            const float* __restrict__ w1, const float* __restrict__ b1,
                            const float* __restrict__ w2, const float* __restrict__ b2,
                            float* __restrict__ style) {
  __shared__ float g[256], s1[512];
  int t = threadIdx.x;
  if (t < 256) g[t] = decf(genc[t]);
  __syncthreads();
  float h = b1[t];
  for (int k = 0; k < 256; k++) h += g[k] * w1[k * 512 + t];
  s1[t] = fmaxf(h, 0.f);
  __syncthreads();
  if (t < 256) {
    float o = b2[t];
    for (int k = 0; k < 512; k++) o += s1[k] * w2[k * 256 + t];
    style[t] = fmaxf(o, 0.f);
  }
}

__global__ void k_tesf(const int* __restrict__ tstep, int b, const float* __restrict__ style,
                       const float* __restrict__ tpw, const float* __restrict__ tpb,
                       const float* __restrict__ spw, const float* __restrict__ spb,
                       float* __restrict__ tesf) {
  __shared__ float te[128], st[256];
  int t = threadIdx.x;
  float tf = (float)tstep[b];
  if (t < 64) {
    const float cfr = (float)(-9.210340371976184 / 63.0);
    float fr = expf((float)t * cfr);
    float ang = tf * fr;
    te[t] = sinf(ang);
    te[64 + t] = cosf(ang);
  }
  st[t] = style[t];
  __syncthreads();
  float v = tpb[t];
  for (int k = 0; k < 128; k++) v += te[k] * tpw[k * 256 + t];
  float v2 = spb[t];
  for (int k = 0; k < 256; k++) v2 += st[k] * spw[k * 256 + t];
  tesf[t] = v + v2;
}

// point encoder, 16 pts/block; pads rows [M_PTS, M_PAD) with zeros
__global__ void k_pet(const float* __restrict__ down,
                      const float* __restrict__ w1, const float* __restrict__ b1,
                      const float* __restrict__ w2, const float* __restrict__ b2,
                      const float* __restrict__ w3, const float* __restrict__ b3,
                      const float* __restrict__ tesf, float* __restrict__ x) {
  __shared__ float pc[16][3];
  __shared__ float l1t[128][20];
  __shared__ float l2t[256][20];
  int t = threadIdx.x;
  int p0 = blockIdx.x * 16;
  if (t < 48) {
    int r = t / 3, cc = t % 3, row = p0 + r;
    pc[r][cc] = (row < M_PTS) ? down[row * 3 + cc] : 0.f;
  }
  __syncthreads();
  {
    int c = t & 127, rg = (t >> 7) * 8;
    float w0 = w1[c], wx = w1[128 + c], wy = w1[256 + c], bb = b1[c];
    #pragma unroll
    for (int j = 0; j < 8; j++) {
      int r = rg + j;
      l1t[c][r] = fmaxf(bb + pc[r][0] * w0 + pc[r][1] * wx + pc[r][2] * wy, 0.f);
    }
  }
  __syncthreads();
  {
    int c = t;
    float acc[16], bb = b2[c];
    #pragma unroll
    for (int j = 0; j < 16; j++) acc[j] = bb;
    for (int k = 0; k < 128; k++) {
      float wv = w2[k * 256 + c];
      #pragma unroll
      for (int h = 0; h < 4; h++) {
        f32x4_t v = *(const f32x4_t*)&l1t[k][h * 4];
        acc[h * 4 + 0] += v[0] * wv; acc[h * 4 + 1] += v[1] * wv;
        acc[h * 4 + 2] += v[2] * wv; acc[h * 4 + 3] += v[3] * wv;
      }
    }
    #pragma unroll
    for (int j = 0; j < 16; j++) l2t[c][j] = fmaxf(acc[j], 0.f);
  }
  __syncthreads();
  {
    int c = t;
    float acc[16], bb = b3[c] + tesf[c];
    #pragma unroll
    for (int j = 0; j < 16; j++) acc[j] = bb;
    for (int k = 0; k < 256; k++) {
      float wv = w3[k * 256 + c];
      #pragma unroll
      for (int h = 0; h < 4; h++) {
        f32x4_t v = *(const f32x4_t*)&l2t[k][h * 4];
        acc[h * 4 + 0] += v[0] * wv; acc[h * 4 + 1] += v[1] * wv;
        acc[h * 4 + 2] += v[2] * wv; acc[h * 4 + 3] += v[3] * wv;
      }
    }
    #pragma unroll
    for (int j = 0; j < 16; j++) {
      int row = p0 + j;
      x[(size_t)row * 256 + c] = (row < M_PTS) ? acc[j] : 0.f;
    }
  }
}

// 6 residual layers via MFMA; 64 rows/block, H in LDS, packed bf16 weights from L2
__global__ __launch_bounds__(256, 2) void k_res6(
    float* __restrict__ xg, const unsigned short* __restrict__ w1p,
    const unsigned short* __restrict__ w2p,
    const float* __restrict__ lb1, const float* __restrict__ lb2) {
  __shared__ unsigned short Hl[64 * 520];
  const int t = threadIdx.x, lane = t & 63, w = t >> 6;
  const int row0 = blockIdx.x * 64;
  const int lr = lane & 15, lg = lane >> 4;
  for (int l = 0; l < 6; l++) {
    const unsigned short* w1l = w1p + (size_t)l * 131072;
    const unsigned short* w2l = w2p + (size_t)l * 131072;
    const float* b1 = lb1 + l * 512;
    const float* b2 = lb2 + l * 256;
    // ---- phase A: H = relu(X @ W1 + b1) -> LDS ----
    {
      f32x4_t acc[4][8];
      #pragma unroll
      for (int mt = 0; mt < 4; mt++)
        #pragma unroll
        for (int ntl = 0; ntl < 8; ntl++) acc[mt][ntl] = 0.f;
      for (int ks = 0; ks < 8; ks++) {
        bf16x8_t af[4];
        #pragma unroll
        for (int mt = 0; mt < 4; mt++) {
          const float* xp = xg + (size_t)(row0 + mt * 16 + lr) * 256 + ks * 32 + lg * 8;
          f32x4_t x0 = *(const f32x4_t*)xp;
          f32x4_t x1 = *(const f32x4_t*)(xp + 4);
          bf16x8_t a;
          a[0] = (short)f2bf(x0[0]); a[1] = (short)f2bf(x0[1]);
          a[2] = (short)f2bf(x0[2]); a[3] = (short)f2bf(x0[3]);
          a[4] = (short)f2bf(x1[0]); a[5] = (short)f2bf(x1[1]);
          a[6] = (short)f2bf(x1[2]); a[7] = (short)f2bf(x1[3]);
          af[mt] = a;
        }
        #pragma unroll
        for (int ntl = 0; ntl < 8; ntl++) {
          const bf16x8_t b = *(const bf16x8_t*)(w1l + ((size_t)(ks * 32 + w * 8 + ntl) * 64 + lane) * 8);
          #pragma unroll
          for (int mt = 0; mt < 4; mt++)
            acc[mt][ntl] = __builtin_amdgcn_mfma_f32_16x16x32_bf16(af[mt], b, acc[mt][ntl], 0, 0, 0);
        }
      }
      #pragma unroll
      for (int ntl = 0; ntl < 8; ntl++) {
        int colg = (w * 8 + ntl) * 16 + lr;
        float bb = b1[colg];
        #pragma unroll
        for (int mt = 0; mt < 4; mt++)
          #pragma unroll
          for (int q = 0; q < 4; q++) {
            int rl = mt * 16 + lg * 4 + q;
            Hl[rl * 520 + colg] = f2bf(fmaxf(acc[mt][ntl][q] + bb, 0.f));
          }
      }
    }
    __syncthreads();
    // ---- phase B: X += H @ W2 + b2 ----
    {
      f32x4_t acc[4][4];
      #pragma unroll
      for (int mt = 0; mt < 4; mt++)
        #pragma unroll
        for (int ntl = 0; ntl < 4; ntl++) acc[mt][ntl] = 0.f;
      for (int ks = 0; ks < 16; ks++) {
        bf16x8_t af[4];
        #pragma unroll
        for (int mt = 0; mt < 4; mt++)
          af[mt] = *(const bf16x8_t*)&Hl[(mt * 16 + lr) * 520 + ks * 32 + lg * 8];
        #pragma unroll
        for (int ntl = 0; ntl < 4; ntl++) {
          const bf16x8_t b = *(const bf16x8_t*)(w2l + ((size_t)(ks * 16 + w * 4 + ntl) * 64 + lane) * 8);
          #pragma unroll
          for (int mt = 0; mt < 4; mt++)
            acc[mt][ntl] = __builtin_amdgcn_mfma_f32_16x16x32_bf16(af[mt], b, acc[mt][ntl], 0, 0, 0);
        }
      }
      #pragma unroll
      for (int ntl = 0; ntl < 4; ntl++) {
        int colg = (w * 4 + ntl) * 16 + lr;
        float bb = b2[colg];
        #pragma unroll
        for (int mt = 0; mt < 4; mt++)
          #pragma unroll
          for (int q = 0; q < 4; q++) {
            int row = row0 + mt * 16 + lg * 4 + q;
            float* xp = xg + (size_t)row * 256 + colg;
            *xp += acc[mt][ntl][q] + bb;
          }
      }
    }
    __threadfence();
    __syncthreads();
  }
}

// fallback residual block (f32, 16 rows/block, in place) if ws too small
__global__ void k_res_old(float* __restrict__ x,
                          const float* __restrict__ w1, const float* __restrict__ b1,
                          const float* __restrict__ w2, const float* __restrict__ b2) {
  __shared__ float xs[RROWS][256];
  __shared__ float hs[RROWS][512];
  int t = threadIdx.x;
  int base = blockIdx.x * RROWS;
  #pragma unroll
  for (int r = 0; r < RROWS; r++) xs[r][t] = x[(size_t)(base + r) * 256 + t];
  __syncthreads();
  float a0[RROWS], a1[RROWS];
  float bj0 = b1[t], bj1 = b1[t + 256];
  #pragma unroll
  for (int r = 0; r < RROWS; r++) { a0[r] = bj0; a1[r] = bj1; }
  for (int k = 0; k < 256; k++) {
    float w0 = w1[k * 512 + t];
    float wq = w1[k * 512 + t + 256];
    #pragma unroll
    for (int r = 0; r < RROWS; r++) {
      float xv = xs[r][k];
      a0[r] += xv * w0;
      a1[r] += xv * wq;
    }
  }
  #pragma unroll
  for (int r = 0; r < RROWS; r++) {
    hs[r][t] = fmaxf(a0[r], 0.f);
    hs[r][t + 256] = fmaxf(a1[r], 0.f);
  }
  __syncthreads();
  float a2[RROWS];
  float bj = b2[t];
  #pragma unroll
  for (int r = 0; r < RROWS; r++) a2[r] = bj;
  for (int k = 0; k < 512; k++) {
    float w = w2[k * 256 + t];
    #pragma unroll
    for (int r = 0; r < RROWS; r++) a2[r] += hs[r][k] * w;
  }
  #pragma unroll
  for (int r = 0; r < RROWS; r++) x[(size_t)(base + r) * 256 + t] = a2[r] + xs[r][t];
}

// output head, 16 pts/block
__global__ void k_outt(const float* __restrict__ x,
                       const float* __restrict__ w1, const float* __restrict__ b1,
                       const float* __restrict__ w2, const float* __restrict__ b2,
                       const float* __restrict__ w3, const float* __restrict__ b3,
                       float* __restrict__ pred) {
  __shared__ float xt[256][20];
  __shared__ float l1t[256][20];
  __shared__ float l2t[128][20];
  int t = threadIdx.x;
  int p0 = blockIdx.x * 16;
  #pragma unroll
  for (int r = 0; r < 16; r++) xt[t][r] = x[(size_t)(p0 + r) * 256 + t];
  __syncthreads();
  {
    int c = t;
    float acc[16], bb = b1[c];
    #pragma unroll
    for (int j = 0; j < 16; j++) acc[j] = bb;
    for (int k = 0; k < 256; k++) {
      float wv = w1[k * 256 + c];
      #pragma unroll
      for (int h = 0; h < 4; h++) {
        f32x4_t v = *(const f32x4_t*)&xt[k][h * 4];
        acc[h * 4 + 0] += v[0] * wv; acc[h * 4 + 1] += v[1] * wv;
        acc[h * 4 + 2] += v[2] * wv; acc[h * 4 + 3] += v[3] * wv;
      }
    }
    #pragma unroll
    for (int j = 0; j < 16; j++) l1t[c][j] = fmaxf(acc[j], 0.f);
  }
  __syncthreads();
  {
    int c = t & 127, rg = (t >> 7) * 8;
    float acc[8], bb = b2[c];
    #pragma unroll
    for (int j = 0; j < 8; j++) acc[j] = bb;
    for (int k = 0; k < 256; k++) {
      float wv = w2[k * 128 + c];
      f32x4_t v0 = *(const f32x4_t*)&l1t[k][rg];
      f32x4_t v1 = *(const f32x4_t*)&l1t[k][rg + 4];
      acc[0] += v0[0] * wv; acc[1] += v0[1] * wv; acc[2] += v0[2] * wv; acc[3] += v0[3] * wv;
      acc[4] += v1[0] * wv; acc[5] += v1[1] * wv; acc[6] += v1[2] * wv; acc[7] += v1[3] * wv;
    }
    #pragma unroll
    for (int j = 0; j < 8; j++) l2t[c][rg + j] = fmaxf(acc[j], 0.f);
  }
  __syncthreads();
  if (t < 48) {
    int r = t / 3, cc = t % 3;
    float acc = b3[cc];
    for (int k = 0; k < 128; k++) acc += l2t[k][r] * w3[k * 3 + cc];
    pred[(size_t)(p0 + r) * 3 + cc] = acc;
  }
}

// ---------------- launch ----------------

extern "C" void kernel_launch(void* const* d_in, const int* in_sizes, int n_in,
                              void* d_out, int out_size, void* d_ws, size_t ws_size,
                              hipStream_t stream) {
  const float* noisy = (const float*)d_in[0];
  const int* tstep = (const int*)d_in[1];
  const float* cond = (const float*)d_in[2];
  const float* se_w1 = (const float*)d_in[3];  const float* se_b1 = (const float*)d_in[4];
  const float* se_w2 = (const float*)d_in[5];  const float* se_b2 = (const float*)d_in[6];
  const float* se_w3 = (const float*)d_in[7];  const float* se_b3 = (const float*)d_in[8];
  const float* sm_w1 = (const float*)d_in[9];  const float* sm_b1 = (const float*)d_in[10];
  const float* sm_w2 = (const float*)d_in[11]; const float* sm_b2 = (const float*)d_in[12];
  const float* pe_w1 = (const float*)d_in[13]; const float* pe_b1 = (const float*)d_in[14];
  const float* pe_w2 = (const float*)d_in[15]; const float* pe_b2 = (const float*)d_in[16];
  const float* pe_w3 = (const float*)d_in[17]; const float* pe_b3 = (const float*)d_in[18];
  const float* tp_w = (const float*)d_in[19];  const float* tp_b = (const float*)d_in[20];
  const float* sp_w = (const float*)d_in[21];  const float* sp_b = (const float*)d_in[22];
  const float* lw1 = (const float*)d_in[23];   const float* lb1 = (const float*)d_in[24];
  const float* lw2 = (const float*)d_in[25];   const float* lb2 = (const float*)d_in[26];
  const float* ow1 = (const float*)d_in[27];   const float* ob1 = (const float*)d_in[28];
  const float* ow2 = (const float*)d_in[29];   const float* ob2 = (const float*)d_in[30];
  const float* ow3 = (const float*)d_in[31];   const float* ob3 = (const float*)d_in[32];

  char* ws = (char*)d_ws;
  unsigned long long* key = (unsigned long long*)(ws + OFF_KEY);
  int* cnt = (int*)(ws + OFF_CNT);
  int* sum = (int*)(ws + OFF_SUM);
  int* sel = (int*)(ws + OFF_SEL);
  Aux* aux = (Aux*)(ws + OFF_AUX);
  float* downC = (float*)(ws + OFF_DOWNC);
  float* downN = (float*)(ws + OFF_DOWNN);
  unsigned* genc = (unsigned*)(ws + OFF_GENC);
  float* style = (float*)(ws + OFF_STYLE);
  float* tesf = (float*)(ws + OFF_TESF);
  float* x = (float*)(ws + OFF_X);
  unsigned short* w1p = (unsigned short*)(ws + OFF_W1P);
  unsigned short* w2p = (unsigned short*)(ws + OFF_W2P);

  float* pred = (float*)d_out;
  float* idxout = (float*)d_out + (size_t)2 * M_PTS * 3;

  const bool use_mfma = (ws_size >= WS_NEED);

  // phase 1: all four downsamples (frees hash scratch before network phase)
  for (int b = 0; b < 2; b++) {
    const float* cp = cond + (size_t)b * N_PTS * 3;
    k_init<<<TS / 256, 256, 0, stream>>>(key, cnt, sum, sel, aux);
    k_minmax<<<256, 256, 0, stream>>>(cp, aux);
    k_vs<<<1, 1, 0, stream>>>(aux);
    k_build<<<(N_PTS + 255) / 256, 256, 0, stream>>>(cp, aux, key, cnt, sum);
    k_reps<<<TS / 256, 256, 0, stream>>>(key, cnt, sum, sel);
    k_select<<<1, 1024, 0, stream>>>(sel, cp, downC + (size_t)b * M_PTS * 3, (float*)nullptr);

    const float* npts = noisy + (size_t)b * N_PTS * 3;
    k_init<<<TS / 256, 256, 0, stream>>>(key, cnt, sum, sel, aux);
    k_minmax<<<256, 256, 0, stream>>>(npts, aux);
    k_vs<<<1, 1, 0, stream>>>(aux);
    k_build<<<(N_PTS + 255) / 256, 256, 0, stream>>>(npts, aux, key, cnt, sum);
    k_reps<<<TS / 256, 256, 0, stream>>>(key, cnt, sum, sel);
    k_select<<<1, 1024, 0, stream>>>(sel, npts, downN + (size_t)b * M_PTS * 3,
                                     idxout + (size_t)b * M_PTS);
  }

  // phase 2: weight packing for MFMA path
  if (use_mfma) {
    k_pack1<<<384, 256, 0, stream>>>(lw1, w1p);
    k_pack2<<<384, 256, 0, stream>>>(lw2, w2p);
  }

  // phase 3: network per batch
  for (int b = 0; b < 2; b++) {
    const float* dc = downC + (size_t)b * M_PTS * 3;
    const float* dn = downN + (size_t)b * M_PTS * 3;
    k_zero_g<<<1, 256, 0, stream>>>(genc);
    k_style_ppt<<<M_PTS / 16, 256, 0, stream>>>(dc, se_w1, se_b1, se_w2, se_b2, se_w3, se_b3, genc);
    k_style_mlp<<<1, 512, 0, stream>>>(genc, sm_w1, sm_b1, sm_w2, sm_b2, style);
    k_tesf<<<1, 256, 0, stream>>>(tstep, b, style, tp_w, tp_b, sp_w, sp_b, tesf);
    k_pet<<<M_PAD / 16, 256, 0, stream>>>(dn, pe_w1, pe_b1, pe_w2, pe_b2, pe_w3, pe_b3, tesf, x);
    if (use_mfma) {
      k_res6<<<M_PAD / 64, 256, 0, stream>>>(x, w1p, w2p, lb1, lb2);
    } else {
      for (int l = 0; l < 6; l++)
        k_res_old<<<M_PAD / RROWS, 256, 0, stream>>>(
            x, lw1 + (size_t)l * 256 * 512, lb1 + (size_t)l * 512,
            lw2 + (size_t)l * 512 * 256, lb2 + (size_t)l * 256);
    }
    k_outt<<<M_PTS / 16, 256, 0, stream>>>(x, ow1, ob1, ow2, ob2, ow3, ob3,
                                           pred + (size_t)b * M_PTS * 3);
  }
}

// Round 3
// 2127.936 us; speedup vs baseline: 5.3346x; 1.5572x over previous
//
#include <hip/hip_runtime.h>
#include <math.h>

#define N_PTS 120000
#define M_PTS 30000
#define NCHUNK 469               // 469 * 64 = 30016 rows (padded)
#define TS (1 << 18)
#define TSM (TS - 1)

typedef __attribute__((ext_vector_type(8))) short bf16x8_t;
typedef __attribute__((ext_vector_type(4))) float f32x4_t;

// ---------------- workspace layout (bytes) ----------------
#define OFF_KEY    0ull
#define OFF_CNT    2097152ull
#define OFF_SUM    3145728ull
#define OFF_SEL    4194304ull            // 120000*4 = 480000
#define OFF_AUX    4674304ull            // 256
#define OFF_DOWNC  4674560ull            // 2*30000*3*4 = 720000
#define OFF_DOWNN  5394560ull            // 720000
#define OFF_GENC   6114560ull            // 1024
#define OFF_STYLE  6115584ull            // 1024
#define OFF_TESF   6116608ull            // 2*256*4 = 2048
#define OFF_PSEW2  6118656ull            // 64*128*2   = 16384
#define OFF_PSEW3  6135040ull            // 128*256*2  = 65536
#define OFF_PPEW2  6200576ull            // 128*256*2  = 65536
#define OFF_PPEW3  6266112ull            // 256*256*2  = 131072
#define OFF_POW1   6397184ull            // 256*256*2  = 131072
#define OFF_POW2   6528256ull            // 256*128*2  = 65536
#define OFF_PLW1   6593792ull            // 6*256*512*2 = 1572864
#define OFF_PLW2   8166656ull            // 1572864
#define WS_NEED    9739520ull

struct Aux {
  unsigned mn_enc[3];
  unsigned mx_enc[3];
  float mn[3];
  float pad;
  double vs;
};

__device__ __forceinline__ unsigned encf(float v) {
  unsigned u = __float_as_uint(v);
  return (u & 0x80000000u) ? ~u : (u | 0x80000000u);
}
__device__ __forceinline__ float decf(unsigned u) {
  unsigned v = (u & 0x80000000u) ? (u & 0x7fffffffu) : ~u;
  return __uint_as_float(v);
}
__device__ __forceinline__ unsigned short f2bf(float f) {
  unsigned u = __float_as_uint(f);
  u += 0x7fffu + ((u >> 16) & 1u);
  return (unsigned short)(u >> 16);
}
// swizzled bf16 store into a [64][512] H tile (row stride 1024 B)
__device__ __forceinline__ void sth(unsigned short* H, int r, int c, unsigned short v) {
  unsigned ad = ((unsigned)(r * 1024 + c * 2)) ^ ((unsigned)(r & 7) << 4);
  *(unsigned short*)((char*)H + ad) = v;
}

// ---------------- downsample kernels ----------------

__global__ void k_init(unsigned long long* __restrict__ key, int* __restrict__ cnt,
                       int* __restrict__ sum, int* __restrict__ sel, Aux* aux) {
  int i = blockIdx.x * blockDim.x + threadIdx.x;
  if (i < TS) { key[i] = 0ull; cnt[i] = 0; sum[i] = 0; }
  if (i < N_PTS) sel[i] = 0;
  if (i < 3) { aux->mn_enc[i] = 0xFFFFFFFFu; aux->mx_enc[i] = 0u; }
}

__global__ void k_minmax(const float* __restrict__ pts, Aux* aux) {
  __shared__ unsigned smn[3], smx[3];
  int t = threadIdx.x;
  if (t < 3) { smn[t] = 0xFFFFFFFFu; smx[t] = 0u; }
  __syncthreads();
  unsigned lmn[3] = {0xFFFFFFFFu, 0xFFFFFFFFu, 0xFFFFFFFFu};
  unsigned lmx[3] = {0u, 0u, 0u};
  for (int i = blockIdx.x * blockDim.x + t; i < N_PTS; i += gridDim.x * blockDim.x) {
    #pragma unroll
    for (int c = 0; c < 3; c++) {
      unsigned e = encf(pts[i * 3 + c]);
      lmn[c] = min(lmn[c], e);
      lmx[c] = max(lmx[c], e);
    }
  }
  #pragma unroll
  for (int c = 0; c < 3; c++) { atomicMin(&smn[c], lmn[c]); atomicMax(&smx[c], lmx[c]); }
  __syncthreads();
  if (t < 3) { atomicMin(&aux->mn_enc[t], smn[t]); atomicMax(&aux->mx_enc[t], smx[t]); }
}

__global__ void k_vs(Aux* aux) {
  double prod = 1.0;
  for (int c = 0; c < 3; c++) {
    float mnf = decf(aux->mn_enc[c]);
    float mxf = decf(aux->mx_enc[c]);
    aux->mn[c] = mnf;
    double r = (double)mxf - (double)mnf;
    if (r < 1e-6) r = 1.0;
    prod *= r;
  }
  double vs = pow(prod / (double)M_PTS, 1.0 / 3.0) * 1.2;
  if (vs < 1e-6) vs = 0.001;
  aux->vs = vs;
}

__global__ void k_build(const float* __restrict__ pts, const Aux* aux,
                        unsigned long long* __restrict__ key, int* __restrict__ cnt,
                        int* __restrict__ sum) {
  int i = blockIdx.x * blockDim.x + threadIdx.x;
  if (i >= N_PTS) return;
  double vs = aux->vs;
  unsigned h = 0u;
  const unsigned mulc[3] = {73856093u, 19349663u, 83492791u};
  #pragma unroll
  for (int c = 0; c < 3; c++) {
    int vi = (int)floor(((double)pts[i * 3 + c] - (double)aux->mn[c]) / vs);
    h ^= (unsigned)vi * mulc[c];
  }
  unsigned long long want = 0x100000000ull | (unsigned long long)h;
  unsigned slot = (h * 2654435761u) >> 14;
  for (;;) {
    unsigned long long cur = key[slot];
    if (cur == want) break;
    if (cur == 0ull) {
      unsigned long long prev = atomicCAS(&key[slot], 0ull, want);
      if (prev == 0ull || prev == want) break;
    }
    slot = (slot + 1) & TSM;
  }
  atomicAdd(&cnt[slot], 1);
  atomicAdd(&sum[slot], i);
}

__global__ void k_reps(const unsigned long long* __restrict__ key, const int* __restrict__ cnt,
                       const int* __restrict__ sum, int* __restrict__ sel) {
  int s = blockIdx.x * blockDim.x + threadIdx.x;
  if (s >= TS) return;
  if (key[s] != 0ull) {
    int rep = sum[s] / cnt[s];
    sel[rep] = 1;
  }
}

__global__ void k_select(const int* __restrict__ sel, const float* __restrict__ pts,
                         float* __restrict__ down, float* __restrict__ idxout) {
  __shared__ int wtot[16], wbase[16];
  __shared__ int Ktot;
  int t = threadIdx.x;
  const int CH = 118;
  int s0 = t * CH;
  int s1 = min(s0 + CH, N_PTS);
  int c = 0;
  for (int i = s0; i < s1; i++) c += sel[i];
  int lane = t & 63, wid = t >> 6;
  int incl = c;
  for (int d = 1; d < 64; d <<= 1) {
    int v = __shfl_up(incl, d, 64);
    if (lane >= d) incl += v;
  }
  if (lane == 63) wtot[wid] = incl;
  __syncthreads();
  if (t == 0) {
    int a = 0;
    for (int k = 0; k < 16; k++) { wbase[k] = a; a += wtot[k]; }
    Ktot = a;
  }
  __syncthreads();
  int excl = wbase[wid] + incl - c;
  int K = Ktot;
  int sr = excl, ur = s0 - excl;
  for (int i = s0; i < s1; i++) {
    int slot = sel[i] ? (sr++) : (K + ur++);
    if (slot < M_PTS) {
      down[slot * 3 + 0] = pts[i * 3 + 0];
      down[slot * 3 + 1] = pts[i * 3 + 1];
      down[slot * 3 + 2] = pts[i * 3 + 2];
      if (idxout) idxout[slot] = (float)i;
    }
  }
}

// ---------------- generic weight packing into MFMA B-frag order ----------------
// dst[((l*KS+ks)*NT+nt)*64+lane][j<8] = W[l][ks*32+(lane>>4)*8+j][nt*16+(lane&15)]
__global__ void k_pack(const float* __restrict__ W, unsigned short* __restrict__ dst,
                       int KS, int NT, int L) {
  int idx = blockIdx.x * 256 + threadIdx.x;
  int total = L * KS * NT * 64;
  if (idx >= total) return;
  int lane = idx & 63;
  int rest = idx >> 6;
  int nt = rest % NT; rest /= NT;
  int ks = rest % KS;
  int l = rest / KS;
  int N = NT * 16, K = KS * 32;
  const float* src = W + (size_t)l * K * N;
  int cc = nt * 16 + (lane & 15);
  int k0 = ks * 32 + ((lane >> 4) << 3);
  unsigned short* d = dst + (size_t)idx * 8;
  #pragma unroll
  for (int j = 0; j < 8; j++) d[j] = f2bf(src[(size_t)(k0 + j) * N + cc]);
}

// ---------------- MFMA helpers ----------------
// A from swizzled bf16 H tile (row stride 1024B), col base cb; K = KS*32, N = NT*16
template <int KS, int NTW, int NT>
__device__ __forceinline__ void mm_h(const unsigned short* __restrict__ Bp,
                                     const unsigned short* __restrict__ H,
                                     int cb, int lane, int w, f32x4_t (&acc)[4][NTW]) {
  int lr = lane & 15, lg = lane >> 4;
  for (int ks = 0; ks < KS; ks++) {
    bf16x8_t af[4];
    #pragma unroll
    for (int mt = 0; mt < 4; mt++) {
      int r = mt * 16 + lr;
      unsigned ad = ((unsigned)(r * 1024 + (cb + ks * 32 + lg * 8) * 2)) ^ ((unsigned)(r & 7) << 4);
      af[mt] = *(const bf16x8_t*)((const char*)H + ad);
    }
    #pragma unroll
    for (int ntl = 0; ntl < NTW; ntl++) {
      bf16x8_t b = *(const bf16x8_t*)(Bp + ((size_t)(ks * NT + w * NTW + ntl) * 64 + lane) * 8);
      #pragma unroll
      for (int mt = 0; mt < 4; mt++)
        acc[mt][ntl] = __builtin_amdgcn_mfma_f32_16x16x32_bf16(af[mt], b, acc[mt][ntl], 0, 0, 0);
    }
  }
}

// A from f32 X tile (row stride 260 floats), K fixed = 256
template <int NTW, int NT>
__device__ __forceinline__ void mm_x(const unsigned short* __restrict__ Bp,
                                     const float* __restrict__ X,
                                     int lane, int w, f32x4_t (&acc)[4][NTW]) {
  int lr = lane & 15, lg = lane >> 4;
  for (int ks = 0; ks < 8; ks++) {
    bf16x8_t af[4];
    #pragma unroll
    for (int mt = 0; mt < 4; mt++) {
      const float* xp = X + (mt * 16 + lr) * 260 + ks * 32 + lg * 8;
      f32x4_t x0 = *(const f32x4_t*)xp;
      f32x4_t x1 = *(const f32x4_t*)(xp + 4);
      bf16x8_t a;
      a[0] = (short)f2bf(x0[0]); a[1] = (short)f2bf(x0[1]);
      a[2] = (short)f2bf(x0[2]); a[3] = (short)f2bf(x0[3]);
      a[4] = (short)f2bf(x1[0]); a[5] = (short)f2bf(x1[1]);
      a[6] = (short)f2bf(x1[2]); a[7] = (short)f2bf(x1[3]);
      af[mt] = a;
    }
    #pragma unroll
    for (int ntl = 0; ntl < NTW; ntl++) {
      bf16x8_t b = *(const bf16x8_t*)(Bp + ((size_t)(ks * NT + w * NTW + ntl) * 64 + lane) * 8);
      #pragma unroll
      for (int mt = 0; mt < 4; mt++)
        acc[mt][ntl] = __builtin_amdgcn_mfma_f32_16x16x32_bf16(af[mt], b, acc[mt][ntl], 0, 0, 0);
    }
  }
}

// ---------------- style encoder (per-point MLP + max pool), MFMA ----------------
__global__ __launch_bounds__(256, 2) void k_style2(
    const float* __restrict__ downC,
    const float* __restrict__ se_w1, const float* __restrict__ se_b1,
    const unsigned short* __restrict__ w2p, const float* __restrict__ se_b2,
    const unsigned short* __restrict__ w3p, const float* __restrict__ se_b3,
    unsigned* __restrict__ genc) {
  __shared__ __attribute__((aligned(16))) unsigned short Hs[64 * 512];
  const int t = threadIdx.x, lane = t & 63, w = t >> 6;
  const int lr = lane & 15, lg = lane >> 4;
  const int row0 = blockIdx.x * 64;
  // L1: 3 -> 64 relu -> bufA cols [0,64)
  {
    int r = t & 63, grow = row0 + r;
    float px = 0.f, py = 0.f, pz = 0.f;
    if (grow < M_PTS) { px = downC[grow * 3]; py = downC[grow * 3 + 1]; pz = downC[grow * 3 + 2]; }
    int c0 = (t >> 6) * 16;
    for (int i = 0; i < 16; i++) {
      int c = c0 + i;
      float v = fmaxf(se_b1[c] + px * se_w1[c] + py * se_w1[64 + c] + pz * se_w1[128 + c], 0.f);
      sth(Hs, r, c, f2bf(v));
    }
  }
  __syncthreads();
  // L2: 64 -> 128 relu -> bufB cols [256,384)
  {
    f32x4_t acc[4][2];
    #pragma unroll
    for (int mt = 0; mt < 4; mt++) { acc[mt][0] = 0.f; acc[mt][1] = 0.f; }
    mm_h<2, 2, 8>(w2p, Hs, 0, lane, w, acc);
    #pragma unroll
    for (int ntl = 0; ntl < 2; ntl++) {
      int col = (w * 2 + ntl) * 16 + lr;
      float bb = se_b2[col];
      #pragma unroll
      for (int mt = 0; mt < 4; mt++)
        #pragma unroll
        for (int q = 0; q < 4; q++)
          sth(Hs, mt * 16 + lg * 4 + q, 256 + col, f2bf(fmaxf(acc[mt][ntl][q] + bb, 0.f)));
    }
  }
  __syncthreads();
  // L3: 128 -> 256 linear; masked max over valid rows; atomicMax into genc
  {
    f32x4_t acc[4][4];
    #pragma unroll
    for (int mt = 0; mt < 4; mt++)
      #pragma unroll
      for (int n = 0; n < 4; n++) acc[mt][n] = 0.f;
    mm_h<4, 4, 16>(w3p, Hs, 256, lane, w, acc);
    #pragma unroll
    for (int ntl = 0; ntl < 4; ntl++) {
      int col = (w * 4 + ntl) * 16 + lr;
      float bb = se_b3[col];
      float m = -3.4e38f;
      #pragma unroll
      for (int mt = 0; mt < 4; mt++)
        #pragma unroll
        for (int q = 0; q < 4; q++) {
          int grow = row0 + mt * 16 + lg * 4 + q;
          float v = acc[mt][ntl][q] + bb;
          if (grow < M_PTS) m = fmaxf(m, v);
        }
      m = fmaxf(m, __shfl_xor(m, 16, 64));
      m = fmaxf(m, __shfl_xor(m, 32, 64));
      if (lg == 0) atomicMax(&genc[col], encf(m));
    }
  }
}

__global__ void k_zero_g(unsigned* __restrict__ g) { g[threadIdx.x] = 0u; }

__global__ void k_style_mlp(const unsigned* __restrict__ genc,
                            const float* __restrict__ w1, const float* __restrict__ b1,
                            const float* __restrict__ w2, const float* __restrict__ b2,
                            float* __restrict__ style) {
  __shared__ float g[256], s1[512];
  int t = threadIdx.x;
  if (t < 256) g[t] = decf(genc[t]);
  __syncthreads();
  float h = b1[t];
  for (int k = 0; k < 256; k++) h += g[k] * w1[k * 512 + t];
  s1[t] = fmaxf(h, 0.f);
  __syncthreads();
  if (t < 256) {
    float o = b2[t];
    for (int k = 0; k < 512; k++) o += s1[k] * w2[k * 256 + t];
    style[t] = fmaxf(o, 0.f);
  }
}

__global__ void k_tesf(const int* __restrict__ tstep, int b, const float* __restrict__ style,
                       const float* __restrict__ tpw, const float* __restrict__ tpb,
                       const float* __restrict__ spw, const float* __restrict__ spb,
                       float* __restrict__ tesf2) {
  __shared__ float te[128], st[256];
  int t = threadIdx.x;
  float tf = (float)tstep[b];
  if (t < 64) {
    const float cfr = (float)(-9.210340371976184 / 63.0);
    float fr = expf((float)t * cfr);
    float ang = tf * fr;
    te[t] = sinf(ang);
    te[64 + t] = cosf(ang);
  }
  st[t] = style[t];
  __syncthreads();
  float v = tpb[t];
  for (int k = 0; k < 128; k++) v += te[k] * tpw[k * 256 + t];
  float v2 = spb[t];
  for (int k = 0; k < 256; k++) v2 += st[k] * spw[k * 256 + t];
  tesf2[b * 256 + t] = v + v2;
}

// ---------------- fused per-point network: pe -> 6x residual -> out head ----------------
// 64 rows/block; X resident in LDS f32; H bf16 XOR-swizzled; O2 overlays X.
__global__ __launch_bounds__(256, 1) void k_net(
    const float* __restrict__ downN, const float* __restrict__ tesf2,
    const float* __restrict__ pe_w1, const float* __restrict__ pe_b1,
    const unsigned short* __restrict__ pw2, const float* __restrict__ pe_b2,
    const unsigned short* __restrict__ pw3, const float* __restrict__ pe_b3,
    const unsigned short* __restrict__ w1p, const float* __restrict__ lb1,
    const unsigned short* __restrict__ w2p, const float* __restrict__ lb2,
    const unsigned short* __restrict__ o1p, const float* __restrict__ ob1,
    const unsigned short* __restrict__ o2p, const float* __restrict__ ob2,
    const float* __restrict__ ow3, const float* __restrict__ ob3,
    float* __restrict__ pred) {
  __shared__ __attribute__((aligned(16))) char POOL[132096];
  float* Xl = (float*)POOL;                                // [64][260] f32
  unsigned short* Hl = (unsigned short*)(POOL + 66560);    // [64][512] bf16 swz
  unsigned short* O2 = (unsigned short*)POOL;              // [64][132] bf16 (after X dead)
  const int t = threadIdx.x, lane = t & 63, w = t >> 6;
  const int lr = lane & 15, lg = lane >> 4;
  const int bt = blockIdx.x / NCHUNK, chunk = blockIdx.x % NCHUNK;
  const int row0 = chunk * 64;
  const float* dn = downN + (size_t)bt * M_PTS * 3;
  const float* tesf = tesf2 + bt * 256;

  // L1: 3 -> 128 relu -> Hl bufA cols [0,128)
  {
    int r = t & 63, grow = row0 + r;
    float px = 0.f, py = 0.f, pz = 0.f;
    if (grow < M_PTS) { px = dn[grow * 3]; py = dn[grow * 3 + 1]; pz = dn[grow * 3 + 2]; }
    int c0 = (t >> 6) * 32;
    for (int i = 0; i < 32; i++) {
      int c = c0 + i;
      float v = fmaxf(pe_b1[c] + px * pe_w1[c] + py * pe_w1[128 + c] + pz * pe_w1[256 + c], 0.f);
      sth(Hl, r, c, f2bf(v));
    }
  }
  __syncthreads();
  // L2: K=128 -> 256 relu -> bufB cols [256,512)
  {
    f32x4_t acc[4][4];
    #pragma unroll
    for (int mt = 0; mt < 4; mt++)
      #pragma unroll
      for (int n = 0; n < 4; n++) acc[mt][n] = 0.f;
    mm_h<4, 4, 16>(pw2, Hl, 0, lane, w, acc);
    #pragma unroll
    for (int ntl = 0; ntl < 4; ntl++) {
      int col = (w * 4 + ntl) * 16 + lr;
      float bb = pe_b2[col];
      #pragma unroll
      for (int mt = 0; mt < 4; mt++)
        #pragma unroll
        for (int q = 0; q < 4; q++)
          sth(Hl, mt * 16 + lg * 4 + q, 256 + col, f2bf(fmaxf(acc[mt][ntl][q] + bb, 0.f)));
    }
  }
  __syncthreads();
  // L3: K=256 (bufB) -> 256 linear + b3 + tesf -> Xl
  {
    f32x4_t acc[4][4];
    #pragma unroll
    for (int mt = 0; mt < 4; mt++)
      #pragma unroll
      for (int n = 0; n < 4; n++) acc[mt][n] = 0.f;
    mm_h<8, 4, 16>(pw3, Hl, 256, lane, w, acc);
    #pragma unroll
    for (int ntl = 0; ntl < 4; ntl++) {
      int col = (w * 4 + ntl) * 16 + lr;
      float bb = pe_b3[col] + tesf[col];
      #pragma unroll
      for (int mt = 0; mt < 4; mt++)
        #pragma unroll
        for (int q = 0; q < 4; q++)
          Xl[(mt * 16 + lg * 4 + q) * 260 + col] = acc[mt][ntl][q] + bb;
    }
  }
  __syncthreads();
  // 6 residual layers
  for (int l = 0; l < 6; l++) {
    {
      f32x4_t acc[4][8];
      #pragma unroll
      for (int mt = 0; mt < 4; mt++)
        #pragma unroll
        for (int n = 0; n < 8; n++) acc[mt][n] = 0.f;
      mm_x<8, 32>(w1p + (size_t)l * 131072, Xl, lane, w, acc);
      #pragma unroll
      for (int ntl = 0; ntl < 8; ntl++) {
        int col = (w * 8 + ntl) * 16 + lr;
        float bb = lb1[l * 512 + col];
        #pragma unroll
        for (int mt = 0; mt < 4; mt++)
          #pragma unroll
          for (int q = 0; q < 4; q++)
            sth(Hl, mt * 16 + lg * 4 + q, col, f2bf(fmaxf(acc[mt][ntl][q] + bb, 0.f)));
      }
    }
    __syncthreads();
    {
      f32x4_t acc[4][4];
      #pragma unroll
      for (int mt = 0; mt < 4; mt++)
        #pragma unroll
        for (int n = 0; n < 4; n++) acc[mt][n] = 0.f;
      mm_h<16, 4, 16>(w2p + (size_t)l * 131072, Hl, 0, lane, w, acc);
      #pragma unroll
      for (int ntl = 0; ntl < 4; ntl++) {
        int col = (w * 4 + ntl) * 16 + lr;
        float bb = lb2[l * 256 + col];
        #pragma unroll
        for (int mt = 0; mt < 4; mt++)
          #pragma unroll
          for (int q = 0; q < 4; q++)
            Xl[(mt * 16 + lg * 4 + q) * 260 + col] += acc[mt][ntl][q] + bb;
      }
    }
    __syncthreads();
  }
  // out1: X -> 256 relu -> Hl bufA
  {
    f32x4_t acc[4][4];
    #pragma unroll
    for (int mt = 0; mt < 4; mt++)
      #pragma unroll
      for (int n = 0; n < 4; n++) acc[mt][n] = 0.f;
    mm_x<4, 16>(o1p, Xl, lane, w, acc);
    #pragma unroll
    for (int ntl = 0; ntl < 4; ntl++) {
      int col = (w * 4 + ntl) * 16 + lr;
      float bb = ob1[col];
      #pragma unroll
      for (int mt = 0; mt < 4; mt++)
        #pragma unroll
        for (int q = 0; q < 4; q++)
          sth(Hl, mt * 16 + lg * 4 + q, col, f2bf(fmaxf(acc[mt][ntl][q] + bb, 0.f)));
    }
  }
  __syncthreads();
  // out2: K=256 (bufA) -> 128 relu -> O2 (overlays dead Xl)
  {
    f32x4_t acc[4][2];
    #pragma unroll
    for (int mt = 0; mt < 4; mt++) { acc[mt][0] = 0.f; acc[mt][1] = 0.f; }
    mm_h<8, 2, 8>(o2p, Hl, 0, lane, w, acc);
    #pragma unroll
    for (int ntl = 0; ntl < 2; ntl++) {
      int col = (w * 2 + ntl) * 16 + lr;
      float bb = ob2[col];
      #pragma unroll
      for (int mt = 0; mt < 4; mt++)
        #pragma unroll
        for (int q = 0; q < 4; q++)
          O2[(mt * 16 + lg * 4 + q) * 132 + col] = f2bf(fmaxf(acc[mt][ntl][q] + bb, 0.f));
    }
  }
  __syncthreads();
  // out3: 128 -> 3
  if (t < 192) {
    int r = t / 3, cc = t % 3, grow = row0 + r;
    if (grow < M_PTS) {
      float acc = ob3[cc];
      for (int k = 0; k < 128; k++)
        acc += __uint_as_float((unsigned)O2[r * 132 + k] << 16) * ow3[k * 3 + cc];
      pred[((size_t)bt * M_PTS + grow) * 3 + cc] = acc;
    }
  }
}

// ---------------- launch ----------------

extern "C" void kernel_launch(void* const* d_in, const int* in_sizes, int n_in,
                              void* d_out, int out_size, void* d_ws, size_t ws_size,
                              hipStream_t stream) {
  const float* noisy = (const float*)d_in[0];
  const int* tstep = (const int*)d_in[1];
  const float* cond = (const float*)d_in[2];
  const float* se_w1 = (const float*)d_in[3];  const float* se_b1 = (const float*)d_in[4];
  const float* se_w2 = (const float*)d_in[5];  const float* se_b2 = (const float*)d_in[6];
  const float* se_w3 = (const float*)d_in[7];  const float* se_b3 = (const float*)d_in[8];
  const float* sm_w1 = (const float*)d_in[9];  const float* sm_b1 = (const float*)d_in[10];
  const float* sm_w2 = (const float*)d_in[11]; const float* sm_b2 = (const float*)d_in[12];
  const float* pe_w1 = (const float*)d_in[13]; const float* pe_b1 = (const float*)d_in[14];
  const float* pe_w2 = (const float*)d_in[15]; const float* pe_b2 = (const float*)d_in[16];
  const float* pe_w3 = (const float*)d_in[17]; const float* pe_b3 = (const float*)d_in[18];
  const float* tp_w = (const float*)d_in[19];  const float* tp_b = (const float*)d_in[20];
  const float* sp_w = (const float*)d_in[21];  const float* sp_b = (const float*)d_in[22];
  const float* lw1 = (const float*)d_in[23];   const float* lb1 = (const float*)d_in[24];
  const float* lw2 = (const float*)d_in[25];   const float* lb2 = (const float*)d_in[26];
  const float* ow1 = (const float*)d_in[27];   const float* ob1 = (const float*)d_in[28];
  const float* ow2 = (const float*)d_in[29];   const float* ob2 = (const float*)d_in[30];
  const float* ow3 = (const float*)d_in[31];   const float* ob3 = (const float*)d_in[32];

  char* ws = (char*)d_ws;
  unsigned long long* key = (unsigned long long*)(ws + OFF_KEY);
  int* cnt = (int*)(ws + OFF_CNT);
  int* sum = (int*)(ws + OFF_SUM);
  int* sel = (int*)(ws + OFF_SEL);
  Aux* aux = (Aux*)(ws + OFF_AUX);
  float* downC = (float*)(ws + OFF_DOWNC);
  float* downN = (float*)(ws + OFF_DOWNN);
  unsigned* genc = (unsigned*)(ws + OFF_GENC);
  float* style = (float*)(ws + OFF_STYLE);
  float* tesf2 = (float*)(ws + OFF_TESF);
  unsigned short* psew2 = (unsigned short*)(ws + OFF_PSEW2);
  unsigned short* psew3 = (unsigned short*)(ws + OFF_PSEW3);
  unsigned short* ppew2 = (unsigned short*)(ws + OFF_PPEW2);
  unsigned short* ppew3 = (unsigned short*)(ws + OFF_PPEW3);
  unsigned short* pow1 = (unsigned short*)(ws + OFF_POW1);
  unsigned short* pow2 = (unsigned short*)(ws + OFF_POW2);
  unsigned short* plw1 = (unsigned short*)(ws + OFF_PLW1);
  unsigned short* plw2 = (unsigned short*)(ws + OFF_PLW2);

  float* pred = (float*)d_out;
  float* idxout = (float*)d_out + (size_t)2 * M_PTS * 3;

  // phase 1: four downsamples
  for (int b = 0; b < 2; b++) {
    const float* cp = cond + (size_t)b * N_PTS * 3;
    k_init<<<TS / 256, 256, 0, stream>>>(key, cnt, sum, sel, aux);
    k_minmax<<<256, 256, 0, stream>>>(cp, aux);
    k_vs<<<1, 1, 0, stream>>>(aux);
    k_build<<<(N_PTS + 255) / 256, 256, 0, stream>>>(cp, aux, key, cnt, sum);
    k_reps<<<TS / 256, 256, 0, stream>>>(key, cnt, sum, sel);
    k_select<<<1, 1024, 0, stream>>>(sel, cp, downC + (size_t)b * M_PTS * 3, (float*)nullptr);

    const float* npts = noisy + (size_t)b * N_PTS * 3;
    k_init<<<TS / 256, 256, 0, stream>>>(key, cnt, sum, sel, aux);
    k_minmax<<<256, 256, 0, stream>>>(npts, aux);
    k_vs<<<1, 1, 0, stream>>>(aux);
    k_build<<<(N_PTS + 255) / 256, 256, 0, stream>>>(npts, aux, key, cnt, sum);
    k_reps<<<TS / 256, 256, 0, stream>>>(key, cnt, sum, sel);
    k_select<<<1, 1024, 0, stream>>>(sel, npts, downN + (size_t)b * M_PTS * 3,
                                     idxout + (size_t)b * M_PTS);
  }

  // phase 2: pack all MFMA weights (bf16 fragment order)
  k_pack<<<4, 256, 0, stream>>>(se_w2, psew2, 2, 8, 1);      // 64x128
  k_pack<<<16, 256, 0, stream>>>(se_w3, psew3, 4, 16, 1);    // 128x256
  k_pack<<<16, 256, 0, stream>>>(pe_w2, ppew2, 4, 16, 1);    // 128x256
  k_pack<<<32, 256, 0, stream>>>(pe_w3, ppew3, 8, 16, 1);    // 256x256
  k_pack<<<32, 256, 0, stream>>>(ow1, pow1, 8, 16, 1);       // 256x256
  k_pack<<<16, 256, 0, stream>>>(ow2, pow2, 8, 8, 1);        // 256x128
  k_pack<<<384, 256, 0, stream>>>(lw1, plw1, 8, 32, 6);      // 6 x 256x512
  k_pack<<<384, 256, 0, stream>>>(lw2, plw2, 16, 16, 6);     // 6 x 512x256

  // phase 3: style -> tesf per batch
  for (int b = 0; b < 2; b++) {
    k_zero_g<<<1, 256, 0, stream>>>(genc);
    k_style2<<<NCHUNK, 256, 0, stream>>>(downC + (size_t)b * M_PTS * 3,
                                         se_w1, se_b1, psew2, se_b2, psew3, se_b3, genc);
    k_style_mlp<<<1, 512, 0, stream>>>(genc, sm_w1, sm_b1, sm_w2, sm_b2, style);
    k_tesf<<<1, 256, 0, stream>>>(tstep, b, style, tp_w, tp_b, sp_w, sp_b, tesf2);
  }

  // phase 4: fused network, both batches
  k_net<<<2 * NCHUNK, 256, 0, stream>>>(downN, tesf2,
                                        pe_w1, pe_b1, ppew2, pe_b2, ppew3, pe_b3,
                                        plw1, lb1, plw2, lb2,
                                        pow1, ob1, pow2, ob2, ow3, ob3, pred);
}

// Round 4
// 1015.943 us; speedup vs baseline: 11.1736x; 2.0945x over previous
//
#include <hip/hip_runtime.h>
#include <math.h>

#define N_PTS 120000
#define M_PTS 30000
#define NCHUNK 469               // 469 * 64 = 30016 rows (padded)
#define TS (1 << 18)
#define TSM (TS - 1)

typedef __attribute__((ext_vector_type(8))) short bf16x8_t;
typedef __attribute__((ext_vector_type(4))) float f32x4_t;

// ---------------- workspace layout (bytes) ----------------
// 4 clouds: c = 2*b + isNoisy  (c0=cond b0, c1=noisy b0, c2=cond b1, c3=noisy b1)
#define OFF_KEY    0ull                   // 4*TS*8  = 8388608
#define OFF_CNT    8388608ull             // 4*TS*4  = 4194304
#define OFF_SUM    12582912ull            // 4194304
#define OFF_SEL    16777216ull            // 4*120000*4 = 1920000
#define OFF_AUX    18697216ull            // 4*64 = 256
#define OFF_DOWN   18697472ull            // 4*30000*3*4 = 1440000
#define OFF_GENC   20137472ull            // 2*256*4 = 2048
#define OFF_STYLE  20139520ull            // 2048
#define OFF_TESF   20141568ull            // 2048
#define OFF_PSEW2  20143616ull            // 16384
#define OFF_PSEW3  20160000ull            // 65536
#define OFF_PPEW2  20225536ull            // 65536
#define OFF_PPEW3  20291072ull            // 131072
#define OFF_POW1   20422144ull            // 131072
#define OFF_POW2   20553216ull            // 65536
#define OFF_PLW1   20618752ull            // 1572864
#define OFF_PLW2   22191616ull            // 1572864
#define WS_NEED    23764480ull

struct Aux {
  unsigned mn_enc[3];
  unsigned mx_enc[3];
  float mn[3];
  float pad;
  double vs;
  double pad2[3];   // -> 64 B
};

__device__ __forceinline__ unsigned encf(float v) {
  unsigned u = __float_as_uint(v);
  return (u & 0x80000000u) ? ~u : (u | 0x80000000u);
}
__device__ __forceinline__ float decf(unsigned u) {
  unsigned v = (u & 0x80000000u) ? (u & 0x7fffffffu) : ~u;
  return __uint_as_float(v);
}
__device__ __forceinline__ unsigned short f2bf(float f) {
  unsigned u = __float_as_uint(f);
  u += 0x7fffu + ((u >> 16) & 1u);
  return (unsigned short)(u >> 16);
}
// swizzled bf16 store into a [64][512] H tile (row stride 1024 B)
__device__ __forceinline__ void sth(unsigned short* H, int r, int c, unsigned short v) {
  unsigned ad = ((unsigned)(r * 1024 + c * 2)) ^ ((unsigned)(r & 7) << 4);
  *(unsigned short*)((char*)H + ad) = v;
}

// ---------------- downsample kernels (4 clouds in parallel) ----------------

__global__ void k_init(unsigned long long* __restrict__ key, int* __restrict__ cnt,
                       int* __restrict__ sum, int* __restrict__ sel, Aux* aux,
                       unsigned* __restrict__ genc) {
  int i = blockIdx.x * blockDim.x + threadIdx.x;
  if (i < 4 * TS) { key[i] = 0ull; cnt[i] = 0; sum[i] = 0; }
  if (i < 4 * N_PTS) sel[i] = 0;
  if (i < 12) { aux[i / 3].mn_enc[i % 3] = 0xFFFFFFFFu; aux[i / 3].mx_enc[i % 3] = 0u; }
  if (i < 512) genc[i] = 0u;
}

__device__ __forceinline__ const float* cloud_ptr(const float* noisy, const float* cond, int c) {
  return ((c & 1) ? noisy : cond) + (size_t)(c >> 1) * N_PTS * 3;
}

__global__ void k_minmax(const float* __restrict__ noisy, const float* __restrict__ cond,
                         Aux* aux) {
  __shared__ unsigned smn[3], smx[3];
  int t = threadIdx.x, c = blockIdx.y;
  const float* pts = cloud_ptr(noisy, cond, c);
  if (t < 3) { smn[t] = 0xFFFFFFFFu; smx[t] = 0u; }
  __syncthreads();
  unsigned lmn[3] = {0xFFFFFFFFu, 0xFFFFFFFFu, 0xFFFFFFFFu};
  unsigned lmx[3] = {0u, 0u, 0u};
  for (int i = blockIdx.x * blockDim.x + t; i < N_PTS; i += gridDim.x * blockDim.x) {
    #pragma unroll
    for (int k = 0; k < 3; k++) {
      unsigned e = encf(pts[i * 3 + k]);
      lmn[k] = min(lmn[k], e);
      lmx[k] = max(lmx[k], e);
    }
  }
  #pragma unroll
  for (int k = 0; k < 3; k++) { atomicMin(&smn[k], lmn[k]); atomicMax(&smx[k], lmx[k]); }
  __syncthreads();
  if (t < 3) { atomicMin(&aux[c].mn_enc[t], smn[t]); atomicMax(&aux[c].mx_enc[t], smx[t]); }
}

__global__ void k_vs(Aux* aux) {
  int c = threadIdx.x;
  if (c >= 4) return;
  double prod = 1.0;
  for (int k = 0; k < 3; k++) {
    float mnf = decf(aux[c].mn_enc[k]);
    float mxf = decf(aux[c].mx_enc[k]);
    aux[c].mn[k] = mnf;
    double r = (double)mxf - (double)mnf;
    if (r < 1e-6) r = 1.0;
    prod *= r;
  }
  double vs = pow(prod / (double)M_PTS, 1.0 / 3.0) * 1.2;
  if (vs < 1e-6) vs = 0.001;
  aux[c].vs = vs;
}

__global__ void k_build(const float* __restrict__ noisy, const float* __restrict__ cond,
                        const Aux* aux, unsigned long long* __restrict__ keyg,
                        int* __restrict__ cntg, int* __restrict__ sumg) {
  int i = blockIdx.x * blockDim.x + threadIdx.x;
  int c = blockIdx.y;
  if (i >= N_PTS) return;
  const float* pts = cloud_ptr(noisy, cond, c);
  unsigned long long* key = keyg + (size_t)c * TS;
  int* cnt = cntg + (size_t)c * TS;
  int* sum = sumg + (size_t)c * TS;
  double vs = aux[c].vs;
  unsigned h = 0u;
  const unsigned mulc[3] = {73856093u, 19349663u, 83492791u};
  #pragma unroll
  for (int k = 0; k < 3; k++) {
    int vi = (int)floor(((double)pts[i * 3 + k] - (double)aux[c].mn[k]) / vs);
    h ^= (unsigned)vi * mulc[k];
  }
  unsigned long long want = 0x100000000ull | (unsigned long long)h;
  unsigned slot = (h * 2654435761u) >> 14;
  for (;;) {
    unsigned long long cur = key[slot];
    if (cur == want) break;
    if (cur == 0ull) {
      unsigned long long prev = atomicCAS(&key[slot], 0ull, want);
      if (prev == 0ull || prev == want) break;
    }
    slot = (slot + 1) & TSM;
  }
  atomicAdd(&cnt[slot], 1);
  atomicAdd(&sum[slot], i);
}

__global__ void k_reps(const unsigned long long* __restrict__ keyg, const int* __restrict__ cntg,
                       const int* __restrict__ sumg, int* __restrict__ selg) {
  int s = blockIdx.x * blockDim.x + threadIdx.x;
  int c = blockIdx.y;
  if (s >= TS) return;
  const unsigned long long* key = keyg + (size_t)c * TS;
  if (key[s] != 0ull) {
    int rep = sumg[(size_t)c * TS + s] / cntg[(size_t)c * TS + s];
    selg[(size_t)c * N_PTS + rep] = 1;
  }
}

// one block of 1024 threads per cloud (grid 4): stable select + gather
__global__ void k_select(const int* __restrict__ selg, const float* __restrict__ noisy,
                         const float* __restrict__ cond, float* __restrict__ downg,
                         float* __restrict__ idxbase) {
  __shared__ int wtot[16], wbase[16];
  __shared__ int Ktot;
  int t = threadIdx.x, c = blockIdx.x;
  const int* sel = selg + (size_t)c * N_PTS;
  const float* pts = cloud_ptr(noisy, cond, c);
  float* down = downg + (size_t)c * M_PTS * 3;
  float* idxout = (c & 1) ? (idxbase + (size_t)(c >> 1) * M_PTS) : nullptr;
  const int CH = 118;
  int s0 = t * CH;
  int s1 = min(s0 + CH, N_PTS);
  int cn = 0;
  for (int i = s0; i < s1; i++) cn += sel[i];
  int lane = t & 63, wid = t >> 6;
  int incl = cn;
  for (int d = 1; d < 64; d <<= 1) {
    int v = __shfl_up(incl, d, 64);
    if (lane >= d) incl += v;
  }
  if (lane == 63) wtot[wid] = incl;
  __syncthreads();
  if (t == 0) {
    int a = 0;
    for (int k = 0; k < 16; k++) { wbase[k] = a; a += wtot[k]; }
    Ktot = a;
  }
  __syncthreads();
  int excl = wbase[wid] + incl - cn;
  int K = Ktot;
  int sr = excl, ur = s0 - excl;
  for (int i = s0; i < s1; i++) {
    int slot = sel[i] ? (sr++) : (K + ur++);
    if (slot < M_PTS) {
      down[slot * 3 + 0] = pts[i * 3 + 0];
      down[slot * 3 + 1] = pts[i * 3 + 1];
      down[slot * 3 + 2] = pts[i * 3 + 2];
      if (idxout) idxout[slot] = (float)i;
    }
  }
}

// ---------------- fused weight packing into MFMA B-frag order ----------------
// dst[((l*KS+ks)*NT+nt)*64+lane][j<8] = W[l][ks*32+(lane>>4)*8+j][nt*16+(lane&15)]
__device__ __forceinline__ void pack_one(const float* __restrict__ W,
                                         unsigned short* __restrict__ dst,
                                         int KS, int NT, int idx) {
  int lane = idx & 63;
  int rest = idx >> 6;
  int nt = rest % NT; rest /= NT;
  int ks = rest % KS;
  int l = rest / KS;
  int N = NT * 16, K = KS * 32;
  const float* src = W + (size_t)l * K * N;
  int cc = nt * 16 + (lane & 15);
  int k0 = ks * 32 + ((lane >> 4) << 3);
  unsigned short* d = dst + (size_t)idx * 8;
  #pragma unroll
  for (int j = 0; j < 8; j++) d[j] = f2bf(src[(size_t)(k0 + j) * N + cc]);
}

__global__ void k_pack_all(
    const float* __restrict__ se_w2, const float* __restrict__ se_w3,
    const float* __restrict__ pe_w2, const float* __restrict__ pe_w3,
    const float* __restrict__ ow1, const float* __restrict__ ow2,
    const float* __restrict__ lw1, const float* __restrict__ lw2,
    unsigned short* __restrict__ psew2, unsigned short* __restrict__ psew3,
    unsigned short* __restrict__ ppew2, unsigned short* __restrict__ ppew3,
    unsigned short* __restrict__ pow1, unsigned short* __restrict__ pow2,
    unsigned short* __restrict__ plw1, unsigned short* __restrict__ plw2) {
  int blk = blockIdx.x;
  const float* W; unsigned short* D; int KS, NT, base;
  if (blk < 4)        { W = se_w2; D = psew2; KS = 2;  NT = 8;  base = 0; }
  else if (blk < 20)  { W = se_w3; D = psew3; KS = 4;  NT = 16; base = 4; }
  else if (blk < 36)  { W = pe_w2; D = ppew2; KS = 4;  NT = 16; base = 20; }
  else if (blk < 68)  { W = pe_w3; D = ppew3; KS = 8;  NT = 16; base = 36; }
  else if (blk < 100) { W = ow1;   D = pow1;  KS = 8;  NT = 16; base = 68; }
  else if (blk < 116) { W = ow2;   D = pow2;  KS = 8;  NT = 8;  base = 100; }
  else if (blk < 500) { W = lw1;   D = plw1;  KS = 8;  NT = 32; base = 116; }
  else                { W = lw2;   D = plw2;  KS = 16; NT = 16; base = 500; }
  pack_one(W, D, KS, NT, (blk - base) * 256 + threadIdx.x);
}

// ---------------- MFMA helpers (W = 8 waves) ----------------
template <int KS, int NTW, int NT>
__device__ __forceinline__ void mm_h(const unsigned short* __restrict__ Bp,
                                     const unsigned short* __restrict__ H,
                                     int cb, int lane, int w, f32x4_t (&acc)[4][NTW]) {
  int lr = lane & 15, lg = lane >> 4;
  for (int ks = 0; ks < KS; ks++) {
    bf16x8_t af[4];
    #pragma unroll
    for (int mt = 0; mt < 4; mt++) {
      int r = mt * 16 + lr;
      unsigned ad = ((unsigned)(r * 1024 + (cb + ks * 32 + lg * 8) * 2)) ^ ((unsigned)(r & 7) << 4);
      af[mt] = *(const bf16x8_t*)((const char*)H + ad);
    }
    #pragma unroll
    for (int ntl = 0; ntl < NTW; ntl++) {
      bf16x8_t b = *(const bf16x8_t*)(Bp + ((size_t)(ks * NT + w * NTW + ntl) * 64 + lane) * 8);
      #pragma unroll
      for (int mt = 0; mt < 4; mt++)
        acc[mt][ntl] = __builtin_amdgcn_mfma_f32_16x16x32_bf16(af[mt], b, acc[mt][ntl], 0, 0, 0);
    }
  }
}

// A from f32 X tile (row stride 260 floats), K fixed = 256
template <int NTW, int NT>
__device__ __forceinline__ void mm_x(const unsigned short* __restrict__ Bp,
                                     const float* __restrict__ X,
                                     int lane, int w, f32x4_t (&acc)[4][NTW]) {
  int lr = lane & 15, lg = lane >> 4;
  for (int ks = 0; ks < 8; ks++) {
    bf16x8_t af[4];
    #pragma unroll
    for (int mt = 0; mt < 4; mt++) {
      const float* xp = X + (mt * 16 + lr) * 260 + ks * 32 + lg * 8;
      f32x4_t x0 = *(const f32x4_t*)xp;
      f32x4_t x1 = *(const f32x4_t*)(xp + 4);
      bf16x8_t a;
      a[0] = (short)f2bf(x0[0]); a[1] = (short)f2bf(x0[1]);
      a[2] = (short)f2bf(x0[2]); a[3] = (short)f2bf(x0[3]);
      a[4] = (short)f2bf(x1[0]); a[5] = (short)f2bf(x1[1]);
      a[6] = (short)f2bf(x1[2]); a[7] = (short)f2bf(x1[3]);
      af[mt] = a;
    }
    #pragma unroll
    for (int ntl = 0; ntl < NTW; ntl++) {
      bf16x8_t b = *(const bf16x8_t*)(Bp + ((size_t)(ks * NT + w * NTW + ntl) * 64 + lane) * 8);
      #pragma unroll
      for (int mt = 0; mt < 4; mt++)
        acc[mt][ntl] = __builtin_amdgcn_mfma_f32_16x16x32_bf16(af[mt], b, acc[mt][ntl], 0, 0, 0);
    }
  }
}

// ---------------- style encoder (per-point MLP + max pool), MFMA, 8 waves ----------------
__global__ __launch_bounds__(512, 2) void k_style2(
    const float* __restrict__ downg,
    const float* __restrict__ se_w1, const float* __restrict__ se_b1,
    const unsigned short* __restrict__ w2p, const float* __restrict__ se_b2,
    const unsigned short* __restrict__ w3p, const float* __restrict__ se_b3,
    unsigned* __restrict__ genc) {
  __shared__ __attribute__((aligned(16))) unsigned short Hs[64 * 512];
  const int t = threadIdx.x, lane = t & 63, w = t >> 6;
  const int lr = lane & 15, lg = lane >> 4;
  const int bt = blockIdx.y;
  const int row0 = blockIdx.x * 64;
  const float* downC = downg + (size_t)(bt << 1) * M_PTS * 3;
  // L1: 3 -> 64 relu -> bufA cols [0,64)
  {
    int r = t & 63, grow = row0 + r;
    float px = 0.f, py = 0.f, pz = 0.f;
    if (grow < M_PTS) { px = downC[grow * 3]; py = downC[grow * 3 + 1]; pz = downC[grow * 3 + 2]; }
    int c0 = (t >> 6) * 8;
    for (int i = 0; i < 8; i++) {
      int c = c0 + i;
      float v = fmaxf(se_b1[c] + px * se_w1[c] + py * se_w1[64 + c] + pz * se_w1[128 + c], 0.f);
      sth(Hs, r, c, f2bf(v));
    }
  }
  __syncthreads();
  // L2: 64 -> 128 relu -> bufB cols [256,384)
  {
    f32x4_t acc[4][1];
    #pragma unroll
    for (int mt = 0; mt < 4; mt++) acc[mt][0] = 0.f;
    mm_h<2, 1, 8>(w2p, Hs, 0, lane, w, acc);
    int col = w * 16 + lr;
    float bb = se_b2[col];
    #pragma unroll
    for (int mt = 0; mt < 4; mt++)
      #pragma unroll
      for (int q = 0; q < 4; q++)
        sth(Hs, mt * 16 + lg * 4 + q, 256 + col, f2bf(fmaxf(acc[mt][0][q] + bb, 0.f)));
  }
  __syncthreads();
  // L3: 128 -> 256 linear; masked max over valid rows; atomicMax into genc
  {
    f32x4_t acc[4][2];
    #pragma unroll
    for (int mt = 0; mt < 4; mt++) { acc[mt][0] = 0.f; acc[mt][1] = 0.f; }
    mm_h<4, 2, 16>(w3p, Hs, 256, lane, w, acc);
    #pragma unroll
    for (int ntl = 0; ntl < 2; ntl++) {
      int col = (w * 2 + ntl) * 16 + lr;
      float bb = se_b3[col];
      float m = -3.4e38f;
      #pragma unroll
      for (int mt = 0; mt < 4; mt++)
        #pragma unroll
        for (int q = 0; q < 4; q++) {
          int grow = row0 + mt * 16 + lg * 4 + q;
          float v = acc[mt][ntl][q] + bb;
          if (grow < M_PTS) m = fmaxf(m, v);
        }
      m = fmaxf(m, __shfl_xor(m, 16, 64));
      m = fmaxf(m, __shfl_xor(m, 32, 64));
      if (lg == 0) atomicMax(&genc[bt * 256 + col], encf(m));
    }
  }
}

// style MLP: 256 -> 512 relu -> 256 relu ; grid 2 (batch), 512 threads
__global__ void k_style_mlp(const unsigned* __restrict__ genc,
                            const float* __restrict__ w1, const float* __restrict__ b1,
                            const float* __restrict__ w2, const float* __restrict__ b2,
                            float* __restrict__ style) {
  __shared__ float g[256], s1[512];
  int t = threadIdx.x, b = blockIdx.x;
  if (t < 256) g[t] = decf(genc[b * 256 + t]);
  __syncthreads();
  float h = b1[t];
  for (int k = 0; k < 256; k++) h += g[k] * w1[k * 512 + t];
  s1[t] = fmaxf(h, 0.f);
  __syncthreads();
  if (t < 256) {
    float o = b2[t];
    for (int k = 0; k < 512; k++) o += s1[k] * w2[k * 256 + t];
    style[b * 256 + t] = fmaxf(o, 0.f);
  }
}

__global__ void k_tesf(const int* __restrict__ tstep, const float* __restrict__ style,
                       const float* __restrict__ tpw, const float* __restrict__ tpb,
                       const float* __restrict__ spw, const float* __restrict__ spb,
                       float* __restrict__ tesf2) {
  __shared__ float te[128], st[256];
  int t = threadIdx.x, b = blockIdx.x;
  float tf = (float)tstep[b];
  if (t < 64) {
    const float cfr = (float)(-9.210340371976184 / 63.0);
    float fr = expf((float)t * cfr);
    float ang = tf * fr;
    te[t] = sinf(ang);
    te[64 + t] = cosf(ang);
  }
  st[t] = style[b * 256 + t];
  __syncthreads();
  float v = tpb[t];
  for (int k = 0; k < 128; k++) v += te[k] * tpw[k * 256 + t];
  float v2 = spb[t];
  for (int k = 0; k < 256; k++) v2 += st[k] * spw[k * 256 + t];
  tesf2[b * 256 + t] = v + v2;
}

// ---------------- fused per-point network: pe -> 6x residual -> out head ----------------
// 64 rows/block, 8 waves; X resident in LDS f32; H bf16 XOR-swizzled; O2 overlays X.
__global__ __launch_bounds__(512, 1) void k_net(
    const float* __restrict__ downg, const float* __restrict__ tesf2,
    const float* __restrict__ pe_w1, const float* __restrict__ pe_b1,
    const unsigned short* __restrict__ pw2, const float* __restrict__ pe_b2,
    const unsigned short* __restrict__ pw3, const float* __restrict__ pe_b3,
    const unsigned short* __restrict__ w1p, const float* __restrict__ lb1,
    const unsigned short* __restrict__ w2p, const float* __restrict__ lb2,
    const unsigned short* __restrict__ o1p, const float* __restrict__ ob1,
    const unsigned short* __restrict__ o2p, const float* __restrict__ ob2,
    const float* __restrict__ ow3, const float* __restrict__ ob3,
    float* __restrict__ pred) {
  __shared__ __attribute__((aligned(16))) char POOL[132096];
  float* Xl = (float*)POOL;                                // [64][260] f32
  unsigned short* Hl = (unsigned short*)(POOL + 66560);    // [64][512] bf16 swz
  unsigned short* O2 = (unsigned short*)POOL;              // [64][132] bf16 (after X dead)
  const int t = threadIdx.x, lane = t & 63, w = t >> 6;
  const int lr = lane & 15, lg = lane >> 4;
  const int bt = blockIdx.y;
  const int row0 = blockIdx.x * 64;
  const float* dn = downg + (size_t)((bt << 1) | 1) * M_PTS * 3;
  const float* tesf = tesf2 + bt * 256;

  // L1: 3 -> 128 relu -> Hl bufA cols [0,128)
  {
    int r = t & 63, grow = row0 + r;
    float px = 0.f, py = 0.f, pz = 0.f;
    if (grow < M_PTS) { px = dn[grow * 3]; py = dn[grow * 3 + 1]; pz = dn[grow * 3 + 2]; }
    int c0 = (t >> 6) * 16;
    for (int i = 0; i < 16; i++) {
      int c = c0 + i;
      float v = fmaxf(pe_b1[c] + px * pe_w1[c] + py * pe_w1[128 + c] + pz * pe_w1[256 + c], 0.f);
      sth(Hl, r, c, f2bf(v));
    }
  }
  __syncthreads();
  // L2: K=128 -> 256 relu -> bufB cols [256,512)
  {
    f32x4_t acc[4][2];
    #pragma unroll
    for (int mt = 0; mt < 4; mt++) { acc[mt][0] = 0.f; acc[mt][1] = 0.f; }
    mm_h<4, 2, 16>(pw2, Hl, 0, lane, w, acc);
    #pragma unroll
    for (int ntl = 0; ntl < 2; ntl++) {
      int col = (w * 2 + ntl) * 16 + lr;
      float bb = pe_b2[col];
      #pragma unroll
      for (int mt = 0; mt < 4; mt++)
        #pragma unroll
        for (int q = 0; q < 4; q++)
          sth(Hl, mt * 16 + lg * 4 + q, 256 + col, f2bf(fmaxf(acc[mt][ntl][q] + bb, 0.f)));
    }
  }
  __syncthreads();
  // L3: K=256 (bufB) -> 256 linear + b3 + tesf -> Xl
  {
    f32x4_t acc[4][2];
    #pragma unroll
    for (int mt = 0; mt < 4; mt++) { acc[mt][0] = 0.f; acc[mt][1] = 0.f; }
    mm_h<8, 2, 16>(pw3, Hl, 256, lane, w, acc);
    #pragma unroll
    for (int ntl = 0; ntl < 2; ntl++) {
      int col = (w * 2 + ntl) * 16 + lr;
      float bb = pe_b3[col] + tesf[col];
      #pragma unroll
      for (int mt = 0; mt < 4; mt++)
        #pragma unroll
        for (int q = 0; q < 4; q++)
          Xl[(mt * 16 + lg * 4 + q) * 260 + col] = acc[mt][ntl][q] + bb;
    }
  }
  __syncthreads();
  // 6 residual layers
  for (int l = 0; l < 6; l++) {
    {
      f32x4_t acc[4][4];
      #pragma unroll
      for (int mt = 0; mt < 4; mt++)
        #pragma unroll
        for (int n = 0; n < 4; n++) acc[mt][n] = 0.f;
      mm_x<4, 32>(w1p + (size_t)l * 131072, Xl, lane, w, acc);
      #pragma unroll
      for (int ntl = 0; ntl < 4; ntl++) {
        int col = (w * 4 + ntl) * 16 + lr;
        float bb = lb1[l * 512 + col];
        #pragma unroll
        for (int mt = 0; mt < 4; mt++)
          #pragma unroll
          for (int q = 0; q < 4; q++)
            sth(Hl, mt * 16 + lg * 4 + q, col, f2bf(fmaxf(acc[mt][ntl][q] + bb, 0.f)));
      }
    }
    __syncthreads();
    {
      f32x4_t acc[4][2];
      #pragma unroll
      for (int mt = 0; mt < 4; mt++) { acc[mt][0] = 0.f; acc[mt][1] = 0.f; }
      mm_h<16, 2, 16>(w2p + (size_t)l * 131072, Hl, 0, lane, w, acc);
      #pragma unroll
      for (int ntl = 0; ntl < 2; ntl++) {
        int col = (w * 2 + ntl) * 16 + lr;
        float bb = lb2[l * 256 + col];
        #pragma unroll
        for (int mt = 0; mt < 4; mt++)
          #pragma unroll
          for (int q = 0; q < 4; q++)
            Xl[(mt * 16 + lg * 4 + q) * 260 + col] += acc[mt][ntl][q] + bb;
      }
    }
    __syncthreads();
  }
  // out1: X -> 256 relu -> Hl bufA
  {
    f32x4_t acc[4][2];
    #pragma unroll
    for (int mt = 0; mt < 4; mt++) { acc[mt][0] = 0.f; acc[mt][1] = 0.f; }
    mm_x<2, 16>(o1p, Xl, lane, w, acc);
    #pragma unroll
    for (int ntl = 0; ntl < 2; ntl++) {
      int col = (w * 2 + ntl) * 16 + lr;
      float bb = ob1[col];
      #pragma unroll
      for (int mt = 0; mt < 4; mt++)
        #pragma unroll
        for (int q = 0; q < 4; q++)
          sth(Hl, mt * 16 + lg * 4 + q, col, f2bf(fmaxf(acc[mt][ntl][q] + bb, 0.f)));
    }
  }
  __syncthreads();
  // out2: K=256 (bufA) -> 128 relu -> O2 (overlays dead Xl)
  {
    f32x4_t acc[4][1];
    #pragma unroll
    for (int mt = 0; mt < 4; mt++) acc[mt][0] = 0.f;
    mm_h<8, 1, 8>(o2p, Hl, 0, lane, w, acc);
    int col = w * 16 + lr;
    float bb = ob2[col];
    #pragma unroll
    for (int mt = 0; mt < 4; mt++)
      #pragma unroll
      for (int q = 0; q < 4; q++)
        O2[(mt * 16 + lg * 4 + q) * 132 + col] = f2bf(fmaxf(acc[mt][0][q] + bb, 0.f));
  }
  __syncthreads();
  // out3: 128 -> 3
  if (t < 192) {
    int r = t / 3, cc = t % 3, grow = row0 + r;
    if (grow < M_PTS) {
      float acc = ob3[cc];
      for (int k = 0; k < 128; k++)
        acc += __uint_as_float((unsigned)O2[r * 132 + k] << 16) * ow3[k * 3 + cc];
      pred[((size_t)bt * M_PTS + grow) * 3 + cc] = acc;
    }
  }
}

// ---------------- launch ----------------

extern "C" void kernel_launch(void* const* d_in, const int* in_sizes, int n_in,
                              void* d_out, int out_size, void* d_ws, size_t ws_size,
                              hipStream_t stream) {
  const float* noisy = (const float*)d_in[0];
  const int* tstep = (const int*)d_in[1];
  const float* cond = (const float*)d_in[2];
  const float* se_w1 = (const float*)d_in[3];  const float* se_b1 = (const float*)d_in[4];
  const float* se_w2 = (const float*)d_in[5];  const float* se_b2 = (const float*)d_in[6];
  const float* se_w3 = (const float*)d_in[7];  const float* se_b3 = (const float*)d_in[8];
  const float* sm_w1 = (const float*)d_in[9];  const float* sm_b1 = (const float*)d_in[10];
  const float* sm_w2 = (const float*)d_in[11]; const float* sm_b2 = (const float*)d_in[12];
  const float* pe_w1 = (const float*)d_in[13]; const float* pe_b1 = (const float*)d_in[14];
  const float* pe_w2 = (const float*)d_in[15]; const float* pe_b2 = (const float*)d_in[16];
  const float* pe_w3 = (const float*)d_in[17]; const float* pe_b3 = (const float*)d_in[18];
  const float* tp_w = (const float*)d_in[19];  const float* tp_b = (const float*)d_in[20];
  const float* sp_w = (const float*)d_in[21];  const float* sp_b = (const float*)d_in[22];
  const float* lw1 = (const float*)d_in[23];   const float* lb1 = (const float*)d_in[24];
  const float* lw2 = (const float*)d_in[25];   const float* lb2 = (const float*)d_in[26];
  const float* ow1 = (const float*)d_in[27];   const float* ob1 = (const float*)d_in[28];
  const float* ow2 = (const float*)d_in[29];   const float* ob2 = (const float*)d_in[30];
  const float* ow3 = (const float*)d_in[31];   const float* ob3 = (const float*)d_in[32];

  char* ws = (char*)d_ws;
  unsigned long long* key = (unsigned long long*)(ws + OFF_KEY);
  int* cnt = (int*)(ws + OFF_CNT);
  int* sum = (int*)(ws + OFF_SUM);
  int* sel = (int*)(ws + OFF_SEL);
  Aux* aux = (Aux*)(ws + OFF_AUX);
  float* down = (float*)(ws + OFF_DOWN);
  unsigned* genc = (unsigned*)(ws + OFF_GENC);
  float* style = (float*)(ws + OFF_STYLE);
  float* tesf2 = (float*)(ws + OFF_TESF);
  unsigned short* psew2 = (unsigned short*)(ws + OFF_PSEW2);
  unsigned short* psew3 = (unsigned short*)(ws + OFF_PSEW3);
  unsigned short* ppew2 = (unsigned short*)(ws + OFF_PPEW2);
  unsigned short* ppew3 = (unsigned short*)(ws + OFF_PPEW3);
  unsigned short* pow1 = (unsigned short*)(ws + OFF_POW1);
  unsigned short* pow2 = (unsigned short*)(ws + OFF_POW2);
  unsigned short* plw1 = (unsigned short*)(ws + OFF_PLW1);
  unsigned short* plw2 = (unsigned short*)(ws + OFF_PLW2);

  float* pred = (float*)d_out;
  float* idxout = (float*)d_out + (size_t)2 * M_PTS * 3;

  // downsample: all 4 clouds in parallel
  k_init<<<4096, 256, 0, stream>>>(key, cnt, sum, sel, aux, genc);
  k_minmax<<<dim3(64, 4), 256, 0, stream>>>(noisy, cond, aux);
  k_vs<<<1, 4, 0, stream>>>(aux);
  k_build<<<dim3(469, 4), 256, 0, stream>>>(noisy, cond, aux, key, cnt, sum);
  k_reps<<<dim3(TS / 256, 4), 256, 0, stream>>>(key, cnt, sum, sel);
  k_select<<<4, 1024, 0, stream>>>(sel, noisy, cond, down, idxout);

  // pack all MFMA weights in one dispatch
  k_pack_all<<<884, 256, 0, stream>>>(se_w2, se_w3, pe_w2, pe_w3, ow1, ow2, lw1, lw2,
                                      psew2, psew3, ppew2, ppew3, pow1, pow2, plw1, plw2);

  // style chain, batch-parallel
  k_style2<<<dim3(NCHUNK, 2), 512, 0, stream>>>(down, se_w1, se_b1, psew2, se_b2,
                                                psew3, se_b3, genc);
  k_style_mlp<<<2, 512, 0, stream>>>(genc, sm_w1, sm_b1, sm_w2, sm_b2, style);
  k_tesf<<<2, 256, 0, stream>>>(tstep, style, tp_w, tp_b, sp_w, sp_b, tesf2);

  // fused network, both batches
  k_net<<<dim3(NCHUNK, 2), 512, 0, stream>>>(down, tesf2,
                                             pe_w1, pe_b1, ppew2, pe_b2, ppew3, pe_b3,
                                             plw1, lb1, plw2, lb2,
                                             pow1, ob1, pow2, ob2, ow3, ob3, pred);
}